// Round 8
// baseline (436.750 us; speedup 1.0000x reference)
//
#include <hip/hip_runtime.h>
#include <stdint.h>

typedef unsigned short u16;
typedef float    f32x4 __attribute__((ext_vector_type(4)));
typedef _Float16 f16x8 __attribute__((ext_vector_type(8)));

__device__ __forceinline__ u16 f2h(float f) {
  _Float16 h = (_Float16)f;  // v_cvt_f16_f32, RNE
  u16 u; __builtin_memcpy(&u, &h, 2); return u;
}
__device__ __forceinline__ float h2f(u16 u) {
  _Float16 h; __builtin_memcpy(&h, &u, 2); return (float)h;
}

// builtin MFMA: no inline-asm register-aliasing hazard under VGPR pressure
__device__ __forceinline__ void mfma_f16(f32x4& c, f16x8 a, f16x8 b) {
  c = __builtin_amdgcn_mfma_f32_16x16x32_f16(a, b, c, 0, 0, 0);
}

// async global->LDS, 16B/lane; LDS dest = wave-uniform base, lane i lands at +i*16B
__device__ __forceinline__ void g2l16(const u16* g, u16* l) {
  __builtin_amdgcn_global_load_lds((const __attribute__((address_space(1))) void*)g,
                                   (__attribute__((address_space(3))) void*)l,
                                   16, 0, 0);
}

// bijective XCD-chunk swizzle (requires gridDim product % 8 == 0; all our grids qualify)
__device__ __forceinline__ void xcd_swz(int& bx, int& by, int& bz) {
  const int gx = gridDim.x, gy = gridDim.y;
  const int n = gx * gy * gridDim.z;
  const int lin = blockIdx.x + gx * (blockIdx.y + gy * blockIdx.z);
  const int q = n >> 3;
  const int s = (lin & 7) * q + (lin >> 3);
  bx = s % gx;
  const int t = s / gx;
  by = t % gy;
  bz = t / gy;
}

struct alignas(8) US4 { u16 a, b, c, d; };

// ---- output: f32 -> f16 hi + lo residual ----
__global__ void k_conv_hilo(const float* __restrict__ src, u16* __restrict__ hi,
                            u16* __restrict__ lo, int n4) {
  int i = blockIdx.x * blockDim.x + threadIdx.x;
  int stride = gridDim.x * blockDim.x;
  for (; i < n4; i += stride) {
    float4 v = reinterpret_cast<const float4*>(src)[i];
    US4 h, l;
    h.a = f2h(v.x); l.a = f2h(v.x - h2f(h.a));
    h.b = f2h(v.y); l.b = f2h(v.y - h2f(h.b));
    h.c = f2h(v.z); l.c = f2h(v.z - h2f(h.c));
    h.d = f2h(v.w); l.d = f2h(v.w - h2f(h.d));
    reinterpret_cast<US4*>(hi)[i] = h;
    reinterpret_cast<US4*>(lo)[i] = l;
  }
}

// ---- 4 weight matrices: f32 -> f16 ----
__global__ void k_conv_w(const float* __restrict__ s_wg, const float* __restrict__ s_ws,
                         const float* __restrict__ s_wt, const float* __restrict__ s_wo,
                         u16* __restrict__ d_wg, u16* __restrict__ d_ws,
                         u16* __restrict__ d_wt, u16* __restrict__ d_wo) {
  constexpr int N1 = 786432;   // 3*1024*1024/4
  constexpr int N2 = 262144;   // 1024*1024/4
  constexpr int total = N1 + 3 * N2;
  int i = blockIdx.x * blockDim.x + threadIdx.x;
  int stride = gridDim.x * blockDim.x;
  for (; i < total; i += stride) {
    const float* s; u16* d; int j;
    if (i < N1)                { s = s_wg; d = d_wg; j = i; }
    else if (i < N1 + N2)      { s = s_ws; d = d_ws; j = i - N1; }
    else if (i < N1 + 2 * N2)  { s = s_wt; d = d_wt; j = i - N1 - N2; }
    else                       { s = s_wo; d = d_wo; j = i - N1 - 2 * N2; }
    float4 v = reinterpret_cast<const float4*>(s)[j];
    US4 h; h.a = f2h(v.x); h.b = f2h(v.y); h.c = f2h(v.z); h.d = f2h(v.w);
    reinterpret_cast<US4*>(d)[j] = h;
  }
}

// ---- encoders: f32 (B,R,C) -> f16 hi, f16 lo, f16 hi^T (B,C,R) ----
__global__ __launch_bounds__(256)
void k_conv_T(const float* __restrict__ src, u16* __restrict__ dh, u16* __restrict__ dl,
              u16* __restrict__ dt, int R, int C) {
  __shared__ u16 t[32][33];
  const int b = blockIdx.z;
  const float* s = src + (size_t)b * R * C;
  u16* dhb = dh + (size_t)b * R * C;
  u16* dlb = dl + (size_t)b * R * C;
  u16* dtb = dt + (size_t)b * R * C;
  const int c0 = blockIdx.x * 32, r0 = blockIdx.y * 32;
  const int tx = threadIdx.x, ty = threadIdx.y;
#pragma unroll
  for (int j = ty; j < 32; j += 8) {
    const size_t idx = (size_t)(r0 + j) * C + (c0 + tx);
    float x = s[idx];
    u16 h = f2h(x);
    dhb[idx] = h;
    dlb[idx] = f2h(x - h2f(h));
    t[j][tx] = h;
  }
  __syncthreads();
#pragma unroll
  for (int j = ty; j < 32; j += 8)
    dtb[(size_t)(c0 + j) * R + (r0 + tx)] = t[tx][j];
}

// ---- softmax (one wave per row): f32 in place + f16 copy ----
template<int L>
__global__ __launch_bounds__(256)
void k_softmax(float* __restrict__ io, u16* __restrict__ pb) {
  const int lane = threadIdx.x & 63;
  const size_t r = (size_t)blockIdx.x * 4 + (threadIdx.x >> 6);
  float* row = io + r * L;
  u16* prow = pb + r * L;
  constexpr int NV = L / 64;
  float v[NV];
  float mx = -3.4e38f;
#pragma unroll
  for (int j = 0; j < NV; ++j) { v[j] = row[lane + j * 64]; mx = fmaxf(mx, v[j]); }
#pragma unroll
  for (int s = 32; s; s >>= 1) mx = fmaxf(mx, __shfl_xor(mx, s));
  float sum = 0.f;
#pragma unroll
  for (int j = 0; j < NV; ++j) { v[j] = __expf(v[j] - mx); sum += v[j]; }
#pragma unroll
  for (int s = 32; s; s >>= 1) sum += __shfl_xor(sum, s);
  const float inv = 1.f / sum;
#pragma unroll
  for (int j = 0; j < NV; ++j) {
    float pv = v[j] * inv;
    row[lane + j * 64] = pv;
    prow[lane + j * 64] = f2h(pv);
  }
}

// ================= GEMM core: BM=128, BN=64, BK=32 =================
// 4 waves in 2x2: wave (wm,wn) owns 64x32 output; acc[4][2] 16x16 frags.
constexpr int BM = 128, BN = 64, BK = 32;

struct TC { int wv, sr, sc, wm, wn, fr, kq; };

__device__ __forceinline__ TC make_tc(int tid) {
  TC t;
  const int lane = tid & 63;
  t.wv = tid >> 6;
  t.sr = lane >> 2;
  t.sc = (lane & 3) * 8;
  t.wm = t.wv >> 1;
  t.wn = t.wv & 1;
  t.fr = lane & 15;
  t.kq = (lane >> 4) * 8;
  return t;
}

// 2-phase double-buffered NT pass: acc += A(0:128, 0:K) * B(0:64, 0:K)^T
// sA = 2*BM*BK dbuf, sB = 2*BN*BK dbuf (ditto sAl/sBl when SPLIT).
template<int SPLIT>
__device__ __forceinline__ void gemm_pass(
    f32x4 (&acc)[8],
    const u16* __restrict__ A, const u16* __restrict__ Al, int lda,
    const u16* __restrict__ B, const u16* __restrict__ Bl, int ldb,
    int K, u16* sA, u16* sAl, u16* sB, u16* sBl, const TC& t)
{
  const int nt = K / BK;
  auto stage = [&](int c, int k0) {
    u16* dA = sA + c * (BM * BK);
    u16* dB = sB + c * (BN * BK);
    const u16* ar = A + (size_t)t.sr * lda + k0 + t.sc;
    const u16* br = B + (size_t)t.sr * ldb + k0 + t.sc;
    g2l16(ar + (size_t)(t.wv * 16) * lda, dA + (t.wv * 16) * BK);
    g2l16(ar + (size_t)((t.wv + 4) * 16) * lda, dA + ((t.wv + 4) * 16) * BK);
    g2l16(br + (size_t)(t.wv * 16) * ldb, dB + (t.wv * 16) * BK);
    if constexpr (SPLIT) {
      u16* dAl = sAl + c * (BM * BK);
      u16* dBl = sBl + c * (BN * BK);
      const u16* alr = Al + (size_t)t.sr * lda + k0 + t.sc;
      const u16* blr = Bl + (size_t)t.sr * ldb + k0 + t.sc;
      g2l16(alr + (size_t)(t.wv * 16) * lda, dAl + (t.wv * 16) * BK);
      g2l16(alr + (size_t)((t.wv + 4) * 16) * lda, dAl + ((t.wv + 4) * 16) * BK);
      g2l16(blr + (size_t)(t.wv * 16) * ldb, dBl + (t.wv * 16) * BK);
    }
  };

  stage(0, 0);
  __syncthreads();           // tile 0 resident
  int c = 0;
  for (int it = 0; it < nt; ++it) {
    if (it + 1 < nt) stage(c ^ 1, (it + 1) * BK);   // async, overlaps MFMA below
    const u16* bA = sA + c * (BM * BK);
    const u16* bB = sB + c * (BN * BK);
    f16x8 ah[4], bh[2];
#pragma unroll
    for (int i = 0; i < 4; ++i)
      ah[i] = *reinterpret_cast<const f16x8*>(&bA[(t.wm * 64 + i * 16 + t.fr) * BK + t.kq]);
#pragma unroll
    for (int j = 0; j < 2; ++j)
      bh[j] = *reinterpret_cast<const f16x8*>(&bB[(t.wn * 32 + j * 16 + t.fr) * BK + t.kq]);
    if constexpr (SPLIT) {
      const u16* bAl = sAl + c * (BM * BK);
      const u16* bBl = sBl + c * (BN * BK);
      f16x8 al[4], bl[2];
#pragma unroll
      for (int i = 0; i < 4; ++i)
        al[i] = *reinterpret_cast<const f16x8*>(&bAl[(t.wm * 64 + i * 16 + t.fr) * BK + t.kq]);
#pragma unroll
      for (int j = 0; j < 2; ++j)
        bl[j] = *reinterpret_cast<const f16x8*>(&bBl[(t.wn * 32 + j * 16 + t.fr) * BK + t.kq]);
#pragma unroll
      for (int i = 0; i < 4; ++i)
#pragma unroll
        for (int j = 0; j < 2; ++j) {
          mfma_f16(acc[i * 2 + j], ah[i], bh[j]);
          mfma_f16(acc[i * 2 + j], al[i], bh[j]);
          mfma_f16(acc[i * 2 + j], ah[i], bl[j]);
        }
    } else {
#pragma unroll
      for (int i = 0; i < 4; ++i)
#pragma unroll
        for (int j = 0; j < 2; ++j)
          mfma_f16(acc[i * 2 + j], ah[i], bh[j]);
    }
    __syncthreads();         // drains next-tile loads + read/write fence
    c ^= 1;
  }
}

// ---- generic NT GEMM kernel ----
// A consumed as nseg segments of segK (A0,A1,A2); B k-index advances globally.
// EPI: 0 Cf=acc (f32); 2 Cb=f16(acc); 6 Cb=f16(sigmoid(acc))
template<int SPLIT, int EPI>
__global__ __launch_bounds__(256, SPLIT ? 3 : 4)
void k_gemm_nt(const u16* __restrict__ A0, const u16* __restrict__ A1, const u16* __restrict__ A2,
               const u16* __restrict__ Alo,
               const u16* __restrict__ Bm, const u16* __restrict__ Blo,
               int lda, int ldb, long long strA, long long strB,
               float* __restrict__ Cf, u16* __restrict__ Cb, int ldc, long long strC,
               int segK, int nseg)
{
  __shared__ __align__(16) u16 sA[2 * BM * BK];
  __shared__ __align__(16) u16 sB[2 * BN * BK];
  __shared__ __align__(16) u16 sAl[SPLIT ? 2 * BM * BK : 8];
  __shared__ __align__(16) u16 sBl[SPLIT ? 2 * BN * BK : 8];

  int bx, by, bz;
  xcd_swz(bx, by, bz);
  const TC t = make_tc(threadIdx.x);

  const size_t aoff = (size_t)((long long)bz * strA) + (size_t)by * BM * lda;
  const size_t boff = (size_t)((long long)bz * strB) + (size_t)bx * BN * ldb;

  f32x4 acc[8];
#pragma unroll
  for (int i = 0; i < 8; ++i) acc[i] = f32x4{0.f, 0.f, 0.f, 0.f};

  const u16* As[3] = {A0, A1, A2};
  for (int s = 0; s < nseg; ++s) {
    gemm_pass<SPLIT>(acc, As[s] + aoff, SPLIT ? Alo + aoff : nullptr, lda,
                     Bm + boff + (size_t)s * segK, SPLIT ? Blo + boff : nullptr, ldb,
                     segK, sA, sAl, sB, sBl, t);
  }

  // epilogue: C/D layout col = lane&15, row = (lane>>4)*4 + reg
  const size_t cbse = (size_t)((long long)bz * strC);
  const int row0 = by * BM + t.wm * 64;
  const int col0 = bx * BN + t.wn * 32;
  const int fq = ((threadIdx.x & 63) >> 4) * 4;
#pragma unroll
  for (int i = 0; i < 4; ++i) {
#pragma unroll
    for (int j = 0; j < 2; ++j) {
      f32x4 v = acc[i * 2 + j];
      const int c = col0 + j * 16 + t.fr;
#pragma unroll
      for (int q = 0; q < 4; ++q) {
        const int r = row0 + i * 16 + fq + q;
        const size_t idx = cbse + (size_t)r * ldc + c;
        if constexpr (EPI == 0) {
          Cf[idx] = v[q];
        } else if constexpr (EPI == 2) {
          Cb[idx] = f2h(v[q]);
        } else {  // EPI == 6
          Cb[idx] = f2h(1.f / (1.f + __expf(-v[q])));
        }
      }
    }
  }
}

// ---- fused fusion kernel: tanh((1-g)*S + g*T + O) with S,T,O chained in registers ----
__global__ __launch_bounds__(256, 4)
void k_fusion(const u16* __restrict__ ctx_s, const u16* __restrict__ ctx_t,
              const u16* __restrict__ outh,
              const u16* __restrict__ Ws, const u16* __restrict__ Wt,
              const u16* __restrict__ Wo,
              const u16* __restrict__ g16, float* __restrict__ fus)
{
  constexpr int H = 1024;
  __shared__ __align__(16) u16 sA[2 * BM * BK];
  __shared__ __align__(16) u16 sB[2 * BN * BK];

  int bx, by, bz;
  xcd_swz(bx, by, bz);
  const TC t = make_tc(threadIdx.x);

  const size_t aoff = (size_t)by * BM * H;
  const size_t boff = (size_t)bx * BN * H;

  const int row0 = by * BM + t.wm * 64;
  const int col0 = bx * BN + t.wn * 32;
  const int fq = ((threadIdx.x & 63) >> 4) * 4;

  f32x4 acc[8];
#pragma unroll
  for (int i = 0; i < 8; ++i) acc[i] = f32x4{0.f, 0.f, 0.f, 0.f};

  // pass 1: S = ctx_s @ Ws^T
  gemm_pass<0>(acc, ctx_s + aoff, nullptr, H, Ws + boff, nullptr, H, H,
               sA, nullptr, sB, nullptr, t);
  f32x4 S[8];
#pragma unroll
  for (int i = 0; i < 8; ++i) { S[i] = acc[i]; acc[i] = f32x4{0.f, 0.f, 0.f, 0.f}; }

  // pass 2: T = ctx_t @ Wt^T, then S = S + g*(T - S)
  gemm_pass<0>(acc, ctx_t + aoff, nullptr, H, Wt + boff, nullptr, H, H,
               sA, nullptr, sB, nullptr, t);
#pragma unroll
  for (int i = 0; i < 4; ++i) {
#pragma unroll
    for (int j = 0; j < 2; ++j) {
      const int c = col0 + j * 16 + t.fr;
#pragma unroll
      for (int q = 0; q < 4; ++q) {
        const int r = row0 + i * 16 + fq + q;
        const float gv = h2f(g16[(size_t)r * H + c]);
        const float sv = S[i * 2 + j][q];
        S[i * 2 + j][q] = sv + gv * (acc[i * 2 + j][q] - sv);
      }
    }
  }
#pragma unroll
  for (int i = 0; i < 8; ++i) acc[i] = f32x4{0.f, 0.f, 0.f, 0.f};

  // pass 3: O = outh @ Wo^T, then write tanh(S + O)
  gemm_pass<0>(acc, outh + aoff, nullptr, H, Wo + boff, nullptr, H, H,
               sA, nullptr, sB, nullptr, t);
#pragma unroll
  for (int i = 0; i < 4; ++i) {
#pragma unroll
    for (int j = 0; j < 2; ++j) {
      const int c = col0 + j * 16 + t.fr;
#pragma unroll
      for (int q = 0; q < 4; ++q) {
        const int r = row0 + i * 16 + fq + q;
        float x = S[i * 2 + j][q] + acc[i * 2 + j][q];
        float ax = fabsf(x);
        float e = __expf(-2.f * ax);
        float th = (1.f - e) / (1.f + e);
        fus[(size_t)r * H + c] = copysignf(th, x);
      }
    }
  }
}

extern "C" void kernel_launch(void* const* d_in, const int* in_sizes, int n_in,
                              void* d_out, int out_size, void* d_ws, size_t ws_size,
                              hipStream_t stream) {
  (void)in_sizes; (void)n_in; (void)out_size; (void)ws_size;
  constexpr int B = 8, T = 1024, S = 1024, St = 512, H = 1024;
  constexpr long long BTH = (long long)B * T * H;
  constexpr long long BSH = (long long)B * S * H;
  constexpr long long BStH = (long long)B * St * H;
  constexpr long long BTS = (long long)B * T * S;
  constexpr long long BTSt = (long long)B * T * St;
  constexpr long long TH = (long long)T * H;

  const float* in_out  = (const float*)d_in[0];
  const float* in_sent = (const float*)d_in[1];
  const float* in_tmpl = (const float*)d_in[2];
  const float* in_Wg   = (const float*)d_in[3];
  const float* in_Ws   = (const float*)d_in[4];
  const float* in_Wt   = (const float*)d_in[5];
  const float* in_Wo   = (const float*)d_in[6];

  float* fus = (float*)d_out;         // (B,T,H)
  float* sw  = fus + BTH;             // (B,T,S)
  float* tw  = sw + BTS;              // (B,T,St)

  // ---- workspace ----
  char* p = (char*)d_ws;
  auto take = [&](long long bytes) { char* q = p; p += bytes; return q; };
  u16* out_h   = (u16*)take(BTH * 2);
  u16* out_lo  = (u16*)take(BTH * 2);
  u16* sent_h  = (u16*)take(BSH * 2);    // dead after sent-logits -> reused as ctx_s
  u16* sent_lo = (u16*)take(BSH * 2);    // dead after sent-logits -> reused as ctx_t
  u16* tmpl_h  = (u16*)take(BStH * 2);
  u16* tmpl_lo = (u16*)take(BStH * 2);
  u16* sentT   = (u16*)take(BSH * 2);    // (B,H,S)
  u16* tmplT   = (u16*)take(BStH * 2);   // (B,H,St)
  u16* Wg_h    = (u16*)take((long long)3 * H * H * 2);
  u16* Ws_h    = (u16*)take((long long)H * H * 2);
  u16* Wt_h    = (u16*)take((long long)H * H * 2);
  u16* Wo_h    = (u16*)take((long long)H * H * 2);
  u16* Ps      = (u16*)take(BTS * 2);
  u16* Pt      = (u16*)take(BTSt * 2);
  u16* g16     = (u16*)take(BTH * 2);    // sigmoid(z) f16

  u16* ctx_s = sent_h;
  u16* ctx_t = sent_lo;

  dim3 thr(256);

  // conversions
  k_conv_hilo<<<2048, 256, 0, stream>>>(in_out, out_h, out_lo, (int)(BTH / 4));
  k_conv_w<<<1024, 256, 0, stream>>>(in_Wg, in_Ws, in_Wt, in_Wo, Wg_h, Ws_h, Wt_h, Wo_h);
  k_conv_T<<<dim3(H / 32, S / 32, B), dim3(32, 8), 0, stream>>>(in_sent, sent_h, sent_lo, sentT, S, H);
  k_conv_T<<<dim3(H / 32, St / 32, B), dim3(32, 8), 0, stream>>>(in_tmpl, tmpl_h, tmpl_lo, tmplT, St, H);

  // logits (3-pass split f16) -> d_out weight slots
  k_gemm_nt<1, 0><<<dim3(S / BN, T / BM, B), thr, 0, stream>>>(
      out_h, nullptr, nullptr, out_lo, sent_h, sent_lo, H, H, TH, (long long)S * H,
      sw, nullptr, S, (long long)T * S, H, 1);
  k_gemm_nt<1, 0><<<dim3(St / BN, T / BM, B), thr, 0, stream>>>(
      out_h, nullptr, nullptr, out_lo, tmpl_h, tmpl_lo, H, H, TH, (long long)St * H,
      tw, nullptr, St, (long long)T * St, H, 1);

  // softmax in place + f16 copy
  k_softmax<1024><<<(B * T) / 4, 256, 0, stream>>>(sw, Ps);
  k_softmax<512><<<(B * T) / 4, 256, 0, stream>>>(tw, Pt);

  // PV -> ctx (f16)
  k_gemm_nt<0, 2><<<dim3(H / BN, T / BM, B), thr, 0, stream>>>(
      Ps, nullptr, nullptr, nullptr, sentT, nullptr, S, S, (long long)T * S, (long long)H * S,
      nullptr, ctx_s, H, TH, S, 1);
  k_gemm_nt<0, 2><<<dim3(H / BN, T / BM, B), thr, 0, stream>>>(
      Pt, nullptr, nullptr, nullptr, tmplT, nullptr, St, St, (long long)T * St, (long long)H * St,
      nullptr, ctx_t, H, TH, St, 1);

  // gate = sigmoid(cat @ Wg^T) as f16, K=3072 via 3 A-segments
  k_gemm_nt<0, 6><<<dim3(H / BN, (B * T) / BM, 1), thr, 0, stream>>>(
      ctx_s, ctx_t, out_h, nullptr, Wg_h, nullptr, H, 3 * H, 0LL, 0LL,
      nullptr, g16, H, 0LL, H, 3);

  // fused fusion: tanh((1-g)*ctx_s@Ws + g*ctx_t@Wt + out@Wo) -> d_out
  k_fusion<<<dim3(H / BN, (B * T) / BM, 1), thr, 0, stream>>>(
      ctx_s, ctx_t, out_h, Ws_h, Wt_h, Wo_h, g16, fus);
}

// Round 9
// 423.682 us; speedup vs baseline: 1.0308x; 1.0308x over previous
//
#include <hip/hip_runtime.h>
#include <stdint.h>

typedef unsigned short u16;
typedef float    f32x4 __attribute__((ext_vector_type(4)));
typedef _Float16 f16x8 __attribute__((ext_vector_type(8)));

__device__ __forceinline__ u16 f2h(float f) {
  _Float16 h = (_Float16)f;  // v_cvt_f16_f32, RNE
  u16 u; __builtin_memcpy(&u, &h, 2); return u;
}
__device__ __forceinline__ float h2f(u16 u) {
  _Float16 h; __builtin_memcpy(&h, &u, 2); return (float)h;
}

__device__ __forceinline__ void mfma_f16(f32x4& c, f16x8 a, f16x8 b) {
  c = __builtin_amdgcn_mfma_f32_16x16x32_f16(a, b, c, 0, 0, 0);
}

// async global->LDS, 16B/lane; LDS dest = wave-uniform base, lane i lands at +i*16B
__device__ __forceinline__ void g2l16(const u16* g, u16* l) {
  __builtin_amdgcn_global_load_lds((const __attribute__((address_space(1))) void*)g,
                                   (__attribute__((address_space(3))) void*)l,
                                   16, 0, 0);
}

template<int N>
__device__ __forceinline__ void s_waitcnt_vm() {
  if constexpr (N == 0) asm volatile("s_waitcnt vmcnt(0)" ::: "memory");
  else if constexpr (N == 1) asm volatile("s_waitcnt vmcnt(1)" ::: "memory");
  else if constexpr (N == 2) asm volatile("s_waitcnt vmcnt(2)" ::: "memory");
  else if constexpr (N == 3) asm volatile("s_waitcnt vmcnt(3)" ::: "memory");
  else if constexpr (N == 4) asm volatile("s_waitcnt vmcnt(4)" ::: "memory");
  else if constexpr (N == 5) asm volatile("s_waitcnt vmcnt(5)" ::: "memory");
  else if constexpr (N == 6) asm volatile("s_waitcnt vmcnt(6)" ::: "memory");
  else if constexpr (N == 8) asm volatile("s_waitcnt vmcnt(8)" ::: "memory");
}

// bijective XCD-chunk swizzle (requires gridDim product % 8 == 0; all our grids qualify)
__device__ __forceinline__ void xcd_swz(int& bx, int& by, int& bz) {
  const int gx = gridDim.x, gy = gridDim.y;
  const int n = gx * gy * gridDim.z;
  const int lin = blockIdx.x + gx * (blockIdx.y + gy * blockIdx.z);
  const int q = n >> 3;
  const int s = (lin & 7) * q + (lin >> 3);
  bx = s % gx;
  const int t = s / gx;
  by = t % gy;
  bz = t / gy;
}

struct alignas(8) US4 { u16 a, b, c, d; };

// ---- output: f32 -> f16 hi + lo residual ----
__global__ void k_conv_hilo(const float* __restrict__ src, u16* __restrict__ hi,
                            u16* __restrict__ lo, int n4) {
  int i = blockIdx.x * blockDim.x + threadIdx.x;
  int stride = gridDim.x * blockDim.x;
  for (; i < n4; i += stride) {
    float4 v = reinterpret_cast<const float4*>(src)[i];
    US4 h, l;
    h.a = f2h(v.x); l.a = f2h(v.x - h2f(h.a));
    h.b = f2h(v.y); l.b = f2h(v.y - h2f(h.b));
    h.c = f2h(v.z); l.c = f2h(v.z - h2f(h.c));
    h.d = f2h(v.w); l.d = f2h(v.w - h2f(h.d));
    reinterpret_cast<US4*>(hi)[i] = h;
    reinterpret_cast<US4*>(lo)[i] = l;
  }
}

// ---- 4 weight matrices: f32 -> f16 ----
__global__ void k_conv_w(const float* __restrict__ s_wg, const float* __restrict__ s_ws,
                         const float* __restrict__ s_wt, const float* __restrict__ s_wo,
                         u16* __restrict__ d_wg, u16* __restrict__ d_ws,
                         u16* __restrict__ d_wt, u16* __restrict__ d_wo) {
  constexpr int N1 = 786432;   // 3*1024*1024/4
  constexpr int N2 = 262144;   // 1024*1024/4
  constexpr int total = N1 + 3 * N2;
  int i = blockIdx.x * blockDim.x + threadIdx.x;
  int stride = gridDim.x * blockDim.x;
  for (; i < total; i += stride) {
    const float* s; u16* d; int j;
    if (i < N1)                { s = s_wg; d = d_wg; j = i; }
    else if (i < N1 + N2)      { s = s_ws; d = d_ws; j = i - N1; }
    else if (i < N1 + 2 * N2)  { s = s_wt; d = d_wt; j = i - N1 - N2; }
    else                       { s = s_wo; d = d_wo; j = i - N1 - 2 * N2; }
    float4 v = reinterpret_cast<const float4*>(s)[j];
    US4 h; h.a = f2h(v.x); h.b = f2h(v.y); h.c = f2h(v.z); h.d = f2h(v.w);
    reinterpret_cast<US4*>(d)[j] = h;
  }
}

// ---- encoders: f32 (B,R,C) -> f16 hi, f16 lo, f16 hi^T (B,C,R) ----
__global__ __launch_bounds__(256)
void k_conv_T(const float* __restrict__ src, u16* __restrict__ dh, u16* __restrict__ dl,
              u16* __restrict__ dt, int R, int C) {
  __shared__ u16 t[32][33];
  const int b = blockIdx.z;
  const float* s = src + (size_t)b * R * C;
  u16* dhb = dh + (size_t)b * R * C;
  u16* dlb = dl + (size_t)b * R * C;
  u16* dtb = dt + (size_t)b * R * C;
  const int c0 = blockIdx.x * 32, r0 = blockIdx.y * 32;
  const int tx = threadIdx.x, ty = threadIdx.y;
#pragma unroll
  for (int j = ty; j < 32; j += 8) {
    const size_t idx = (size_t)(r0 + j) * C + (c0 + tx);
    float x = s[idx];
    u16 h = f2h(x);
    dhb[idx] = h;
    dlb[idx] = f2h(x - h2f(h));
    t[j][tx] = h;
  }
  __syncthreads();
#pragma unroll
  for (int j = ty; j < 32; j += 8)
    dtb[(size_t)(c0 + j) * R + (r0 + tx)] = t[tx][j];
}

// ---- softmax (one wave per row): f32 in place + f16 copy ----
template<int L>
__global__ __launch_bounds__(256)
void k_softmax(float* __restrict__ io, u16* __restrict__ pb) {
  const int lane = threadIdx.x & 63;
  const size_t r = (size_t)blockIdx.x * 4 + (threadIdx.x >> 6);
  float* row = io + r * L;
  u16* prow = pb + r * L;
  constexpr int NV = L / 64;
  float v[NV];
  float mx = -3.4e38f;
#pragma unroll
  for (int j = 0; j < NV; ++j) { v[j] = row[lane + j * 64]; mx = fmaxf(mx, v[j]); }
#pragma unroll
  for (int s = 32; s; s >>= 1) mx = fmaxf(mx, __shfl_xor(mx, s));
  float sum = 0.f;
#pragma unroll
  for (int j = 0; j < NV; ++j) { v[j] = __expf(v[j] - mx); sum += v[j]; }
#pragma unroll
  for (int s = 32; s; s >>= 1) sum += __shfl_xor(sum, s);
  const float inv = 1.f / sum;
#pragma unroll
  for (int j = 0; j < NV; ++j) {
    float pv = v[j] * inv;
    row[lane + j * 64] = pv;
    prow[lane + j * 64] = f2h(pv);
  }
}

// ================= GEMM core =================
// BM=128 always. BNN=128 (non-split, 16 MFMA/wave/step) or 64 (split, 24/step).
// 4 waves 2x2; wave (wm,wn) owns 64 x (BNN/2) output.
constexpr int BM = 128, BK = 32;

struct TC { int wv, sr, sc, wm, wn, fr, kq; };

__device__ __forceinline__ TC make_tc(int tid) {
  TC t;
  const int lane = tid & 63;
  t.wv = tid >> 6;
  t.sr = lane >> 2;
  t.sc = (lane & 3) * 8;
  t.wm = t.wv >> 1;
  t.wn = t.wv & 1;
  t.fr = lane & 15;
  t.kq = (lane >> 4) * 8;
  return t;
}

// 3-deep pipelined NT pass with counted vmcnt: acc += A(0:128,0:K) * B(0:BNN,0:K)^T
// LDS buffers are 3-deep: sA[3*BM*BK], sB[3*BNN*BK] (ditto sAl/sBl when SPLIT).
template<int SPLIT, int BNN>
__device__ __forceinline__ void gemm_pass(
    f32x4* acc,                       // [4 * (BNN/32)]
    const u16* __restrict__ A, const u16* __restrict__ Al, int lda,
    const u16* __restrict__ B, const u16* __restrict__ Bl, int ldb,
    int K, u16* sA, u16* sAl, u16* sB, u16* sBl, const TC& t)
{
  constexpr int NB  = BNN / 32;                       // b-frags per wave
  constexpr int BCH = BNN / 64;                       // B stage chunks (1 or 2)
  constexpr int LPS = (2 + BCH) * (SPLIT ? 2 : 1);    // vmem ops per stage per wave
  constexpr int ASZ = BM * BK, BSZ = BNN * BK;
  const int nt = K / BK;

  auto stage = [&](int c, int k0) {
    u16* dA = sA + c * ASZ;
    u16* dB = sB + c * BSZ;
    const u16* ar = A + (size_t)t.sr * lda + k0 + t.sc;
    const u16* br = B + (size_t)t.sr * ldb + k0 + t.sc;
    g2l16(ar + (size_t)(t.wv * 16) * lda, dA + (t.wv * 16) * BK);
    g2l16(ar + (size_t)((t.wv + 4) * 16) * lda, dA + ((t.wv + 4) * 16) * BK);
    g2l16(br + (size_t)(t.wv * 16) * ldb, dB + (t.wv * 16) * BK);
    if constexpr (BCH == 2)
      g2l16(br + (size_t)((t.wv + 4) * 16) * ldb, dB + ((t.wv + 4) * 16) * BK);
    if constexpr (SPLIT) {
      u16* dAl = sAl + c * ASZ;
      u16* dBl = sBl + c * BSZ;
      const u16* alr = Al + (size_t)t.sr * lda + k0 + t.sc;
      const u16* blr = Bl + (size_t)t.sr * ldb + k0 + t.sc;
      g2l16(alr + (size_t)(t.wv * 16) * lda, dAl + (t.wv * 16) * BK);
      g2l16(alr + (size_t)((t.wv + 4) * 16) * lda, dAl + ((t.wv + 4) * 16) * BK);
      g2l16(blr + (size_t)(t.wv * 16) * ldb, dBl + (t.wv * 16) * BK);
      if constexpr (BCH == 2)
        g2l16(blr + (size_t)((t.wv + 4) * 16) * ldb, dBl + ((t.wv + 4) * 16) * BK);
    }
  };

  // prologue: tiles 0 and 1 in flight; wait for tile 0 only (older ops retire first)
  stage(0, 0);
  stage(1, BK);
  s_waitcnt_vm<LPS>();
  __builtin_amdgcn_s_barrier();
  __builtin_amdgcn_sched_barrier(0);

  for (int it = 0; it < nt; ++it) {
    const int cb = it % 3;
    if (it + 2 < nt) stage((it + 2) % 3, (it + 2) * BK);   // stays in flight across barrier

    const u16* bA = sA + cb * ASZ;
    const u16* bB = sB + cb * BSZ;
    f16x8 ah[4], bh[NB];
#pragma unroll
    for (int i = 0; i < 4; ++i)
      ah[i] = *reinterpret_cast<const f16x8*>(&bA[(t.wm * 64 + i * 16 + t.fr) * BK + t.kq]);
#pragma unroll
    for (int j = 0; j < NB; ++j)
      bh[j] = *reinterpret_cast<const f16x8*>(&bB[(t.wn * (BNN / 2) + j * 16 + t.fr) * BK + t.kq]);
    if constexpr (SPLIT) {
      const u16* bAl = sAl + cb * ASZ;
      const u16* bBl = sBl + cb * BSZ;
      f16x8 al[4], bl[NB];
#pragma unroll
      for (int i = 0; i < 4; ++i)
        al[i] = *reinterpret_cast<const f16x8*>(&bAl[(t.wm * 64 + i * 16 + t.fr) * BK + t.kq]);
#pragma unroll
      for (int j = 0; j < NB; ++j)
        bl[j] = *reinterpret_cast<const f16x8*>(&bBl[(t.wn * (BNN / 2) + j * 16 + t.fr) * BK + t.kq]);
#pragma unroll
      for (int i = 0; i < 4; ++i)
#pragma unroll
        for (int j = 0; j < NB; ++j) {
          mfma_f16(acc[i * NB + j], ah[i], bh[j]);
          mfma_f16(acc[i * NB + j], al[i], bh[j]);
          mfma_f16(acc[i * NB + j], ah[i], bl[j]);
        }
    } else {
#pragma unroll
      for (int i = 0; i < 4; ++i)
#pragma unroll
        for (int j = 0; j < NB; ++j)
          mfma_f16(acc[i * NB + j], ah[i], bh[j]);
    }

    // counted wait: next tile's loads complete, tile-after-next stays in flight
    if (it + 2 < nt)      s_waitcnt_vm<LPS>();
    else if (it + 1 < nt) s_waitcnt_vm<0>();
    __builtin_amdgcn_s_barrier();
    __builtin_amdgcn_sched_barrier(0);
  }
}

// ---- generic NT GEMM kernel ----
// A consumed as nseg segments of segK (A0,A1,A2); B k-index advances globally.
// EPI: 0 Cf=acc (f32); 2 Cb=f16(acc); 6 Cb=f16(sigmoid(acc))
template<int SPLIT, int EPI>
__global__ __launch_bounds__(256, 2)
void k_gemm_nt(const u16* __restrict__ A0, const u16* __restrict__ A1, const u16* __restrict__ A2,
               const u16* __restrict__ Alo,
               const u16* __restrict__ Bm, const u16* __restrict__ Blo,
               int lda, int ldb, long long strA, long long strB,
               float* __restrict__ Cf, u16* __restrict__ Cb, int ldc, long long strC,
               int segK, int nseg)
{
  constexpr int BNN = SPLIT ? 64 : 128;
  constexpr int NB = BNN / 32;
  __shared__ __align__(16) u16 sA[3 * BM * BK];
  __shared__ __align__(16) u16 sB[3 * BNN * BK];
  __shared__ __align__(16) u16 sAl[SPLIT ? 3 * BM * BK : 8];
  __shared__ __align__(16) u16 sBl[SPLIT ? 3 * BNN * BK : 8];

  int bx, by, bz;
  xcd_swz(bx, by, bz);
  const TC t = make_tc(threadIdx.x);

  const size_t aoff = (size_t)((long long)bz * strA) + (size_t)by * BM * lda;
  const size_t boff = (size_t)((long long)bz * strB) + (size_t)bx * BNN * ldb;

  f32x4 acc[4 * NB];
#pragma unroll
  for (int i = 0; i < 4 * NB; ++i) acc[i] = f32x4{0.f, 0.f, 0.f, 0.f};

  const u16* As[3] = {A0, A1, A2};
  for (int s = 0; s < nseg; ++s) {
    gemm_pass<SPLIT, BNN>(acc, As[s] + aoff, SPLIT ? Alo + aoff : nullptr, lda,
                          Bm + boff + (size_t)s * segK, SPLIT ? Blo + boff : nullptr, ldb,
                          segK, sA, sAl, sB, sBl, t);
  }

  // epilogue: C/D layout col = lane&15, row = (lane>>4)*4 + reg
  const size_t cbse = (size_t)((long long)bz * strC);
  const int row0 = by * BM + t.wm * 64;
  const int col0 = bx * BNN + t.wn * (BNN / 2);
  const int fq = ((threadIdx.x & 63) >> 4) * 4;
#pragma unroll
  for (int i = 0; i < 4; ++i) {
#pragma unroll
    for (int j = 0; j < NB; ++j) {
      f32x4 v = acc[i * NB + j];
      const int c = col0 + j * 16 + t.fr;
#pragma unroll
      for (int q = 0; q < 4; ++q) {
        const int r = row0 + i * 16 + fq + q;
        const size_t idx = cbse + (size_t)r * ldc + c;
        if constexpr (EPI == 0) {
          Cf[idx] = v[q];
        } else if constexpr (EPI == 2) {
          Cb[idx] = f2h(v[q]);
        } else {  // EPI == 6
          Cb[idx] = f2h(1.f / (1.f + __expf(-v[q])));
        }
      }
    }
  }
}

// ---- fused fusion kernel: tanh((1-g)*S + g*T + O) with S,T,O chained in registers ----
__global__ __launch_bounds__(256, 2)
void k_fusion(const u16* __restrict__ ctx_s, const u16* __restrict__ ctx_t,
              const u16* __restrict__ outh,
              const u16* __restrict__ Ws, const u16* __restrict__ Wt,
              const u16* __restrict__ Wo,
              const u16* __restrict__ g16, float* __restrict__ fus)
{
  constexpr int H = 1024;
  __shared__ __align__(16) u16 sA[3 * BM * BK];
  __shared__ __align__(16) u16 sB[3 * 128 * BK];

  int bx, by, bz;
  xcd_swz(bx, by, bz);
  const TC t = make_tc(threadIdx.x);

  const size_t aoff = (size_t)by * BM * H;
  const size_t boff = (size_t)bx * 128 * H;

  const int row0 = by * BM + t.wm * 64;
  const int col0 = bx * 128 + t.wn * 64;
  const int fq = ((threadIdx.x & 63) >> 4) * 4;

  f32x4 acc[16];
#pragma unroll
  for (int i = 0; i < 16; ++i) acc[i] = f32x4{0.f, 0.f, 0.f, 0.f};

  // pass 1: S = ctx_s @ Ws^T
  gemm_pass<0, 128>(acc, ctx_s + aoff, nullptr, H, Ws + boff, nullptr, H, H,
                    sA, nullptr, sB, nullptr, t);
  f32x4 S[16];
#pragma unroll
  for (int i = 0; i < 16; ++i) { S[i] = acc[i]; acc[i] = f32x4{0.f, 0.f, 0.f, 0.f}; }

  // pass 2: T = ctx_t @ Wt^T, then S = S + g*(T - S)
  gemm_pass<0, 128>(acc, ctx_t + aoff, nullptr, H, Wt + boff, nullptr, H, H,
                    sA, nullptr, sB, nullptr, t);
#pragma unroll
  for (int i = 0; i < 4; ++i) {
#pragma unroll
    for (int j = 0; j < 4; ++j) {
      const int c = col0 + j * 16 + t.fr;
#pragma unroll
      for (int q = 0; q < 4; ++q) {
        const int r = row0 + i * 16 + fq + q;
        const float gv = h2f(g16[(size_t)r * H + c]);
        const float sv = S[i * 4 + j][q];
        S[i * 4 + j][q] = sv + gv * (acc[i * 4 + j][q] - sv);
      }
    }
  }
#pragma unroll
  for (int i = 0; i < 16; ++i) acc[i] = f32x4{0.f, 0.f, 0.f, 0.f};

  // pass 3: O = outh @ Wo^T, then write tanh(S + O)
  gemm_pass<0, 128>(acc, outh + aoff, nullptr, H, Wo + boff, nullptr, H, H,
                    sA, nullptr, sB, nullptr, t);
#pragma unroll
  for (int i = 0; i < 4; ++i) {
#pragma unroll
    for (int j = 0; j < 4; ++j) {
      const int c = col0 + j * 16 + t.fr;
#pragma unroll
      for (int q = 0; q < 4; ++q) {
        const int r = row0 + i * 16 + fq + q;
        float x = S[i * 4 + j][q] + acc[i * 4 + j][q];
        float ax = fabsf(x);
        float e = __expf(-2.f * ax);
        float th = (1.f - e) / (1.f + e);
        fus[(size_t)r * H + c] = copysignf(th, x);
      }
    }
  }
}

extern "C" void kernel_launch(void* const* d_in, const int* in_sizes, int n_in,
                              void* d_out, int out_size, void* d_ws, size_t ws_size,
                              hipStream_t stream) {
  (void)in_sizes; (void)n_in; (void)out_size; (void)ws_size;
  constexpr int B = 8, T = 1024, S = 1024, St = 512, H = 1024;
  constexpr long long BTH = (long long)B * T * H;
  constexpr long long BSH = (long long)B * S * H;
  constexpr long long BStH = (long long)B * St * H;
  constexpr long long BTS = (long long)B * T * S;
  constexpr long long BTSt = (long long)B * T * St;
  constexpr long long TH = (long long)T * H;

  const float* in_out  = (const float*)d_in[0];
  const float* in_sent = (const float*)d_in[1];
  const float* in_tmpl = (const float*)d_in[2];
  const float* in_Wg   = (const float*)d_in[3];
  const float* in_Ws   = (const float*)d_in[4];
  const float* in_Wt   = (const float*)d_in[5];
  const float* in_Wo   = (const float*)d_in[6];

  float* fus = (float*)d_out;         // (B,T,H)
  float* sw  = fus + BTH;             // (B,T,S)
  float* tw  = sw + BTS;              // (B,T,St)

  // ---- workspace ----
  char* p = (char*)d_ws;
  auto take = [&](long long bytes) { char* q = p; p += bytes; return q; };
  u16* out_h   = (u16*)take(BTH * 2);
  u16* out_lo  = (u16*)take(BTH * 2);
  u16* sent_h  = (u16*)take(BSH * 2);    // dead after sent-logits -> reused as ctx_s
  u16* sent_lo = (u16*)take(BSH * 2);    // dead after sent-logits -> reused as ctx_t
  u16* tmpl_h  = (u16*)take(BStH * 2);
  u16* tmpl_lo = (u16*)take(BStH * 2);
  u16* sentT   = (u16*)take(BSH * 2);    // (B,H,S)
  u16* tmplT   = (u16*)take(BStH * 2);   // (B,H,St)
  u16* Wg_h    = (u16*)take((long long)3 * H * H * 2);
  u16* Ws_h    = (u16*)take((long long)H * H * 2);
  u16* Wt_h    = (u16*)take((long long)H * H * 2);
  u16* Wo_h    = (u16*)take((long long)H * H * 2);
  u16* Ps      = (u16*)take(BTS * 2);
  u16* Pt      = (u16*)take(BTSt * 2);
  u16* g16     = (u16*)take(BTH * 2);    // sigmoid(z) f16

  u16* ctx_s = sent_h;
  u16* ctx_t = sent_lo;

  dim3 thr(256);

  // conversions
  k_conv_hilo<<<2048, 256, 0, stream>>>(in_out, out_h, out_lo, (int)(BTH / 4));
  k_conv_w<<<1024, 256, 0, stream>>>(in_Wg, in_Ws, in_Wt, in_Wo, Wg_h, Ws_h, Wt_h, Wo_h);
  k_conv_T<<<dim3(H / 32, S / 32, B), dim3(32, 8), 0, stream>>>(in_sent, sent_h, sent_lo, sentT, S, H);
  k_conv_T<<<dim3(H / 32, St / 32, B), dim3(32, 8), 0, stream>>>(in_tmpl, tmpl_h, tmpl_lo, tmplT, St, H);

  // logits (3-pass split f16, BN=64 depth-3) -> d_out weight slots
  k_gemm_nt<1, 0><<<dim3(S / 64, T / BM, B), thr, 0, stream>>>(
      out_h, nullptr, nullptr, out_lo, sent_h, sent_lo, H, H, TH, (long long)S * H,
      sw, nullptr, S, (long long)T * S, H, 1);
  k_gemm_nt<1, 0><<<dim3(St / 64, T / BM, B), thr, 0, stream>>>(
      out_h, nullptr, nullptr, out_lo, tmpl_h, tmpl_lo, H, H, TH, (long long)St * H,
      tw, nullptr, St, (long long)T * St, H, 1);

  // softmax in place + f16 copy
  k_softmax<1024><<<(B * T) / 4, 256, 0, stream>>>(sw, Ps);
  k_softmax<512><<<(B * T) / 4, 256, 0, stream>>>(tw, Pt);

  // PV -> ctx (f16), BN=128 depth-3
  k_gemm_nt<0, 2><<<dim3(H / 128, T / BM, B), thr, 0, stream>>>(
      Ps, nullptr, nullptr, nullptr, sentT, nullptr, S, S, (long long)T * S, (long long)H * S,
      nullptr, ctx_s, H, TH, S, 1);
  k_gemm_nt<0, 2><<<dim3(H / 128, T / BM, B), thr, 0, stream>>>(
      Pt, nullptr, nullptr, nullptr, tmplT, nullptr, St, St, (long long)T * St, (long long)H * St,
      nullptr, ctx_t, H, TH, St, 1);

  // gate = sigmoid(cat @ Wg^T) as f16, K=3072 via 3 A-segments
  k_gemm_nt<0, 6><<<dim3(H / 128, (B * T) / BM, 1), thr, 0, stream>>>(
      ctx_s, ctx_t, out_h, nullptr, Wg_h, nullptr, H, 3 * H, 0LL, 0LL,
      nullptr, g16, H, 0LL, H, 3);

  // fused fusion: tanh((1-g)*ctx_s@Ws + g*ctx_t@Wt + out@Wo) -> d_out
  k_fusion<<<dim3(H / 128, (B * T) / BM, 1), thr, 0, stream>>>(
      ctx_s, ctx_t, out_h, Ws_h, Wt_h, Wo_h, g16, fus);
}

// Round 10
// 401.238 us; speedup vs baseline: 1.0885x; 1.0559x over previous
//
#include <hip/hip_runtime.h>
#include <stdint.h>

typedef unsigned short u16;
typedef float    f32x4 __attribute__((ext_vector_type(4)));
typedef _Float16 f16x8 __attribute__((ext_vector_type(8)));
typedef _Float16 f16x4 __attribute__((ext_vector_type(4)));

__device__ __forceinline__ u16 f2h(float f) {
  _Float16 h = (_Float16)f;  // v_cvt_f16_f32, RNE
  u16 u; __builtin_memcpy(&u, &h, 2); return u;
}
__device__ __forceinline__ float h2f(u16 u) {
  _Float16 h; __builtin_memcpy(&h, &u, 2); return (float)h;
}

__device__ __forceinline__ void mfma_f16(f32x4& c, f16x8 a, f16x8 b) {
  c = __builtin_amdgcn_mfma_f32_16x16x32_f16(a, b, c, 0, 0, 0);
}

// async global->LDS, 16B/lane; LDS dest = wave-uniform base, lane i lands at +i*16B
__device__ __forceinline__ void g2l16(const u16* g, u16* l) {
  __builtin_amdgcn_global_load_lds((const __attribute__((address_space(1))) void*)g,
                                   (__attribute__((address_space(3))) void*)l,
                                   16, 0, 0);
}

// batch-chunk swizzle: XCD owns slowest-dim chunk (PV/logits: one batch per XCD -> L2 fit)
__device__ __forceinline__ void xcd_batch(int& bx, int& by, int& bz) {
  const int gx = gridDim.x, gy = gridDim.y;
  const int n = gx * gy * gridDim.z;
  const int lin = blockIdx.x + gx * (blockIdx.y + gy * blockIdx.z);
  const int q = n >> 3;
  const int s = (lin & 7) * q + (lin >> 3);
  bx = s % gx;
  const int t2 = s / gx;
  by = t2 % gy;
  bz = t2 / gy;
}

// column-strip swizzle for 2D grids: XCD owns one bx strip -> weight panel L2-resident
__device__ __forceinline__ void xcd_col(int& bx, int& by) {
  const int gx = gridDim.x, gy = gridDim.y;
  const int n = gx * gy;
  const int cpx = n >> 3;
  const int lin = blockIdx.x + gx * blockIdx.y;
  const int s = (lin & 7) * cpx + (lin >> 3);
  bx = s / gy;       // strip index (constant per XCD when gx==8)
  by = s % gy;
}

struct alignas(8) US4 { u16 a, b, c, d; };

// ---- output: f32 -> f16 hi + lo residual ----
__global__ void k_conv_hilo(const float* __restrict__ src, u16* __restrict__ hi,
                            u16* __restrict__ lo, int n4) {
  int i = blockIdx.x * blockDim.x + threadIdx.x;
  int stride = gridDim.x * blockDim.x;
  for (; i < n4; i += stride) {
    float4 v = reinterpret_cast<const float4*>(src)[i];
    US4 h, l;
    h.a = f2h(v.x); l.a = f2h(v.x - h2f(h.a));
    h.b = f2h(v.y); l.b = f2h(v.y - h2f(h.b));
    h.c = f2h(v.z); l.c = f2h(v.z - h2f(h.c));
    h.d = f2h(v.w); l.d = f2h(v.w - h2f(h.d));
    reinterpret_cast<US4*>(hi)[i] = h;
    reinterpret_cast<US4*>(lo)[i] = l;
  }
}

// ---- 4 weight matrices: f32 -> f16 ----
__global__ void k_conv_w(const float* __restrict__ s_wg, const float* __restrict__ s_ws,
                         const float* __restrict__ s_wt, const float* __restrict__ s_wo,
                         u16* __restrict__ d_wg, u16* __restrict__ d_ws,
                         u16* __restrict__ d_wt, u16* __restrict__ d_wo) {
  constexpr int N1 = 786432;   // 3*1024*1024/4
  constexpr int N2 = 262144;   // 1024*1024/4
  constexpr int total = N1 + 3 * N2;
  int i = blockIdx.x * blockDim.x + threadIdx.x;
  int stride = gridDim.x * blockDim.x;
  for (; i < total; i += stride) {
    const float* s; u16* d; int j;
    if (i < N1)                { s = s_wg; d = d_wg; j = i; }
    else if (i < N1 + N2)      { s = s_ws; d = d_ws; j = i - N1; }
    else if (i < N1 + 2 * N2)  { s = s_wt; d = d_wt; j = i - N1 - N2; }
    else                       { s = s_wo; d = d_wo; j = i - N1 - 2 * N2; }
    float4 v = reinterpret_cast<const float4*>(s)[j];
    US4 h; h.a = f2h(v.x); h.b = f2h(v.y); h.c = f2h(v.z); h.d = f2h(v.w);
    reinterpret_cast<US4*>(d)[j] = h;
  }
}

// ---- encoders: f32 (B,R,C) -> f16 hi, f16 lo, f16 hi^T (B,C,R) ----
__global__ __launch_bounds__(256)
void k_conv_T(const float* __restrict__ src, u16* __restrict__ dh, u16* __restrict__ dl,
              u16* __restrict__ dt, int R, int C) {
  __shared__ u16 t[32][33];
  const int b = blockIdx.z;
  const float* s = src + (size_t)b * R * C;
  u16* dhb = dh + (size_t)b * R * C;
  u16* dlb = dl + (size_t)b * R * C;
  u16* dtb = dt + (size_t)b * R * C;
  const int c0 = blockIdx.x * 32, r0 = blockIdx.y * 32;
  const int tx = threadIdx.x, ty = threadIdx.y;
#pragma unroll
  for (int j = ty; j < 32; j += 8) {
    const size_t idx = (size_t)(r0 + j) * C + (c0 + tx);
    float x = s[idx];
    u16 h = f2h(x);
    dhb[idx] = h;
    dlb[idx] = f2h(x - h2f(h));
    t[j][tx] = h;
  }
  __syncthreads();
#pragma unroll
  for (int j = ty; j < 32; j += 8)
    dtb[(size_t)(c0 + j) * R + (r0 + tx)] = t[tx][j];
}

// ---- softmax (one wave per row): f32 in place + f16 copy ----
template<int L>
__global__ __launch_bounds__(256)
void k_softmax(float* __restrict__ io, u16* __restrict__ pb) {
  const int lane = threadIdx.x & 63;
  const size_t r = (size_t)blockIdx.x * 4 + (threadIdx.x >> 6);
  float* row = io + r * L;
  u16* prow = pb + r * L;
  constexpr int NV = L / 64;
  float v[NV];
  float mx = -3.4e38f;
#pragma unroll
  for (int j = 0; j < NV; ++j) { v[j] = row[lane + j * 64]; mx = fmaxf(mx, v[j]); }
#pragma unroll
  for (int s = 32; s; s >>= 1) mx = fmaxf(mx, __shfl_xor(mx, s));
  float sum = 0.f;
#pragma unroll
  for (int j = 0; j < NV; ++j) { v[j] = __expf(v[j] - mx); sum += v[j]; }
#pragma unroll
  for (int s = 32; s; s >>= 1) sum += __shfl_xor(sum, s);
  const float inv = 1.f / sum;
#pragma unroll
  for (int j = 0; j < NV; ++j) {
    float pv = v[j] * inv;
    row[lane + j * 64] = pv;
    prow[lane + j * 64] = f2h(pv);
  }
}

// ================= GEMM cores (BM=BN=128, 4 waves 2x2, 64x64 per wave) =================
struct TC { int wv, sr, sc, wm, wn, fr, kq; };

__device__ __forceinline__ TC make_tc(int tid) {
  TC t;
  const int lane = tid & 63;
  t.wv = tid >> 6;
  t.sr = lane >> 2;
  t.sc = (lane & 3) * 8;
  t.wm = t.wv >> 1;
  t.wn = t.wv & 1;
  t.fr = lane & 15;
  t.kq = (lane >> 4) * 8;
  return t;
}

constexpr int SUB = 128 * 32;   // one [128][32] sub-tile (8 KB)

// ---- pass64: 2-phase dbuf, BK=64 as two [128][32] sub-tiles (bank-clean ds_read) ----
// sA, sB each 2 bufs * 2 subs * SUB elems (32 KB each).
__device__ __forceinline__ void pass64(
    f32x4 (&acc)[16],
    const u16* __restrict__ A, int lda,
    const u16* __restrict__ B, int ldb,
    int K, u16* sA, u16* sB, const TC& t)
{
  const int nt = K / 64;
  auto stage = [&](int c, int k0) {
#pragma unroll
    for (int sub = 0; sub < 2; ++sub) {
      u16* dA = sA + c * (2 * SUB) + sub * SUB;
      u16* dB = sB + c * (2 * SUB) + sub * SUB;
      const u16* ar = A + (size_t)t.sr * lda + k0 + sub * 32 + t.sc;
      const u16* br = B + (size_t)t.sr * ldb + k0 + sub * 32 + t.sc;
      g2l16(ar + (size_t)(t.wv * 16) * lda, dA + (t.wv * 16) * 32);
      g2l16(ar + (size_t)((t.wv + 4) * 16) * lda, dA + ((t.wv + 4) * 16) * 32);
      g2l16(br + (size_t)(t.wv * 16) * ldb, dB + (t.wv * 16) * 32);
      g2l16(br + (size_t)((t.wv + 4) * 16) * ldb, dB + ((t.wv + 4) * 16) * 32);
    }
  };

  stage(0, 0);
  __syncthreads();
  int c = 0;
  for (int it = 0; it < nt; ++it) {
    if (it + 1 < nt) stage(c ^ 1, (it + 1) * 64);   // overlaps MFMA below
#pragma unroll
    for (int sub = 0; sub < 2; ++sub) {
      const u16* bA = sA + c * (2 * SUB) + sub * SUB;
      const u16* bB = sB + c * (2 * SUB) + sub * SUB;
      f16x8 ah[4], bh[4];
#pragma unroll
      for (int i = 0; i < 4; ++i) {
        ah[i] = *reinterpret_cast<const f16x8*>(&bA[(t.wm * 64 + i * 16 + t.fr) * 32 + t.kq]);
        bh[i] = *reinterpret_cast<const f16x8*>(&bB[(t.wn * 64 + i * 16 + t.fr) * 32 + t.kq]);
      }
#pragma unroll
      for (int i = 0; i < 4; ++i)
#pragma unroll
        for (int j = 0; j < 4; ++j)
          mfma_f16(acc[i * 4 + j], ah[i], bh[j]);
    }
    __syncthreads();
    c ^= 1;
  }
}

// ---- pass32s: hi/lo split (3 MFMA/frag), 2-phase dbuf, BK=32 (round-6 proven) ----
__device__ __forceinline__ void pass32s(
    f32x4 (&acc)[16],
    const u16* __restrict__ A, const u16* __restrict__ Al, int lda,
    const u16* __restrict__ B, const u16* __restrict__ Bl, int ldb,
    int K, u16* sA, u16* sAl, u16* sB, u16* sBl, const TC& t)
{
  const int nt = K / 32;
  auto stage = [&](int c, int k0) {
    u16* dA = sA + c * SUB;  u16* dB = sB + c * SUB;
    u16* dAl = sAl + c * SUB; u16* dBl = sBl + c * SUB;
    const u16* ar = A + (size_t)t.sr * lda + k0 + t.sc;
    const u16* br = B + (size_t)t.sr * ldb + k0 + t.sc;
    const u16* alr = Al + (size_t)t.sr * lda + k0 + t.sc;
    const u16* blr = Bl + (size_t)t.sr * ldb + k0 + t.sc;
    g2l16(ar + (size_t)(t.wv * 16) * lda, dA + (t.wv * 16) * 32);
    g2l16(ar + (size_t)((t.wv + 4) * 16) * lda, dA + ((t.wv + 4) * 16) * 32);
    g2l16(br + (size_t)(t.wv * 16) * ldb, dB + (t.wv * 16) * 32);
    g2l16(br + (size_t)((t.wv + 4) * 16) * ldb, dB + ((t.wv + 4) * 16) * 32);
    g2l16(alr + (size_t)(t.wv * 16) * lda, dAl + (t.wv * 16) * 32);
    g2l16(alr + (size_t)((t.wv + 4) * 16) * lda, dAl + ((t.wv + 4) * 16) * 32);
    g2l16(blr + (size_t)(t.wv * 16) * ldb, dBl + (t.wv * 16) * 32);
    g2l16(blr + (size_t)((t.wv + 4) * 16) * ldb, dBl + ((t.wv + 4) * 16) * 32);
  };

  stage(0, 0);
  __syncthreads();
  int c = 0;
  for (int it = 0; it < nt; ++it) {
    if (it + 1 < nt) stage(c ^ 1, (it + 1) * 32);
    const u16* bA = sA + c * SUB;  const u16* bB = sB + c * SUB;
    const u16* bAl = sAl + c * SUB; const u16* bBl = sBl + c * SUB;
    f16x8 ah[4], bh[4], al[4], bl[4];
#pragma unroll
    for (int i = 0; i < 4; ++i) {
      ah[i] = *reinterpret_cast<const f16x8*>(&bA[(t.wm * 64 + i * 16 + t.fr) * 32 + t.kq]);
      bh[i] = *reinterpret_cast<const f16x8*>(&bB[(t.wn * 64 + i * 16 + t.fr) * 32 + t.kq]);
      al[i] = *reinterpret_cast<const f16x8*>(&bAl[(t.wm * 64 + i * 16 + t.fr) * 32 + t.kq]);
      bl[i] = *reinterpret_cast<const f16x8*>(&bBl[(t.wn * 64 + i * 16 + t.fr) * 32 + t.kq]);
    }
#pragma unroll
    for (int i = 0; i < 4; ++i)
#pragma unroll
      for (int j = 0; j < 4; ++j) {
        mfma_f16(acc[i * 4 + j], ah[i], bh[j]);
        mfma_f16(acc[i * 4 + j], al[i], bh[j]);
        mfma_f16(acc[i * 4 + j], ah[i], bl[j]);
      }
    __syncthreads();
    c ^= 1;
  }
}

// ---- logits: split hi/lo, f32 out (grid: (N/128, T/128, B); XCD = batch) ----
__global__ __launch_bounds__(256, 2)
void k_logits(const u16* __restrict__ Ah, const u16* __restrict__ Al,
              const u16* __restrict__ Bh, const u16* __restrict__ Bl,
              long long strB, float* __restrict__ Cf, int ldc, long long strC)
{
  __shared__ __align__(16) u16 sA[2 * SUB], sB[2 * SUB], sAl[2 * SUB], sBl[2 * SUB];
  int bx, by, bz;
  xcd_batch(bx, by, bz);
  const TC t = make_tc(threadIdx.x);

  const size_t aoff = (size_t)bz * (1024 * 1024) + (size_t)by * 128 * 1024;
  const size_t boff = (size_t)bz * strB + (size_t)bx * 128 * 1024;

  f32x4 acc[16];
#pragma unroll
  for (int i = 0; i < 16; ++i) acc[i] = f32x4{0.f, 0.f, 0.f, 0.f};

  pass32s(acc, Ah + aoff, Al + aoff, 1024, Bh + boff, Bl + boff, 1024, 1024,
          sA, sAl, sB, sBl, t);

  const size_t cbse = (size_t)bz * strC;
  const int row0 = by * 128 + t.wm * 64;
  const int col0 = bx * 128 + t.wn * 64;
  const int fq = ((threadIdx.x & 63) >> 4) * 4;
#pragma unroll
  for (int i = 0; i < 4; ++i)
#pragma unroll
    for (int j = 0; j < 4; ++j) {
      const int c = col0 + j * 16 + t.fr;
#pragma unroll
      for (int q = 0; q < 4; ++q)
        Cf[cbse + (size_t)(row0 + i * 16 + fq + q) * ldc + c] = acc[i * 4 + j][q];
    }
}

// ---- PV: f16 out (grid: (8, 8, B); XCD = batch -> Ps+sentT = 4MB = L2) ----
__global__ __launch_bounds__(256, 2)
void k_pv(const u16* __restrict__ A, const u16* __restrict__ Bt, int ld,
          long long strA, long long strB, u16* __restrict__ Cb, long long strC)
{
  __shared__ __align__(16) u16 sA[2 * 2 * SUB], sB[2 * 2 * SUB];
  int bx, by, bz;
  xcd_batch(bx, by, bz);
  const TC t = make_tc(threadIdx.x);

  f32x4 acc[16];
#pragma unroll
  for (int i = 0; i < 16; ++i) acc[i] = f32x4{0.f, 0.f, 0.f, 0.f};

  pass64(acc, A + (size_t)bz * strA + (size_t)by * 128 * ld, ld,
         Bt + (size_t)bz * strB + (size_t)bx * 128 * ld, ld, ld, sA, sB, t);

  const size_t cbse = (size_t)bz * strC;
  const int row0 = by * 128 + t.wm * 64;
  const int col0 = bx * 128 + t.wn * 64;
  const int fq = ((threadIdx.x & 63) >> 4) * 4;
#pragma unroll
  for (int i = 0; i < 4; ++i)
#pragma unroll
    for (int j = 0; j < 4; ++j) {
      const int c = col0 + j * 16 + t.fr;
#pragma unroll
      for (int q = 0; q < 4; ++q)
        Cb[cbse + (size_t)(row0 + i * 16 + fq + q) * 1024 + c] = f2h(acc[i * 4 + j][q]);
    }
}

// ---- fusion4: z -> g(regs) -> S -> T(apply g) -> O -> tanh, one kernel ----
// grid (8, 64); col-strip swizzle pins all W strips (1.5 MB) in the XCD's L2.
__global__ __launch_bounds__(256, 2)
void k_fusion4(const u16* __restrict__ ctx_s, const u16* __restrict__ ctx_t,
               const u16* __restrict__ outh,
               const u16* __restrict__ Wg, const u16* __restrict__ Ws,
               const u16* __restrict__ Wt, const u16* __restrict__ Wo,
               float* __restrict__ fus)
{
  constexpr int H = 1024;
  __shared__ __align__(16) u16 sA[2 * 2 * SUB], sB[2 * 2 * SUB];

  int bx, by;
  xcd_col(bx, by);
  const TC t = make_tc(threadIdx.x);

  const size_t aoff = (size_t)by * 128 * H;
  const int row0 = by * 128 + t.wm * 64;
  const int col0 = bx * 128 + t.wn * 64;
  const int fq = ((threadIdx.x & 63) >> 4) * 4;

  f32x4 acc[16];
#pragma unroll
  for (int i = 0; i < 16; ++i) acc[i] = f32x4{0.f, 0.f, 0.f, 0.f};

  // pass z: gate pre-activation over K=3072 (3 A segments), B strip = Wg rows
  const u16* As[3] = {ctx_s, ctx_t, outh};
  for (int s = 0; s < 3; ++s)
    pass64(acc, As[s] + aoff, H, Wg + (size_t)bx * 128 * (3 * H) + s * H, 3 * H, H,
           sA, sB, t);
  f16x4 gh[16];
#pragma unroll
  for (int f = 0; f < 16; ++f)
#pragma unroll
    for (int q = 0; q < 4; ++q)
      gh[f][q] = (_Float16)(1.f / (1.f + __expf(-acc[f][q])));

  // pass S
#pragma unroll
  for (int i = 0; i < 16; ++i) acc[i] = f32x4{0.f, 0.f, 0.f, 0.f};
  pass64(acc, ctx_s + aoff, H, Ws + (size_t)bx * 128 * H, H, H, sA, sB, t);
  f32x4 S[16];
#pragma unroll
  for (int i = 0; i < 16; ++i) { S[i] = acc[i]; acc[i] = f32x4{0.f, 0.f, 0.f, 0.f}; }

  // pass T, then S = S + g*(T - S)
  pass64(acc, ctx_t + aoff, H, Wt + (size_t)bx * 128 * H, H, H, sA, sB, t);
#pragma unroll
  for (int f = 0; f < 16; ++f)
#pragma unroll
    for (int q = 0; q < 4; ++q) {
      const float gv = (float)gh[f][q];
      const float sv = S[f][q];
      S[f][q] = sv + gv * (acc[f][q] - sv);
    }
#pragma unroll
  for (int i = 0; i < 16; ++i) acc[i] = f32x4{0.f, 0.f, 0.f, 0.f};

  // pass O, then write tanh(S + O)
  pass64(acc, outh + aoff, H, Wo + (size_t)bx * 128 * H, H, H, sA, sB, t);
#pragma unroll
  for (int i = 0; i < 4; ++i)
#pragma unroll
    for (int j = 0; j < 4; ++j) {
      const int c = col0 + j * 16 + t.fr;
#pragma unroll
      for (int q = 0; q < 4; ++q) {
        const int r = row0 + i * 16 + fq + q;
        float x = S[i * 4 + j][q] + acc[i * 4 + j][q];
        float ax = fabsf(x);
        float e = __expf(-2.f * ax);
        float th = (1.f - e) / (1.f + e);
        fus[(size_t)r * H + c] = copysignf(th, x);
      }
    }
}

extern "C" void kernel_launch(void* const* d_in, const int* in_sizes, int n_in,
                              void* d_out, int out_size, void* d_ws, size_t ws_size,
                              hipStream_t stream) {
  (void)in_sizes; (void)n_in; (void)out_size; (void)ws_size;
  constexpr int B = 8, T = 1024, S = 1024, St = 512, H = 1024;
  constexpr long long BTH = (long long)B * T * H;
  constexpr long long BSH = (long long)B * S * H;
  constexpr long long BStH = (long long)B * St * H;
  constexpr long long BTS = (long long)B * T * S;
  constexpr long long BTSt = (long long)B * T * St;
  constexpr long long TH = (long long)T * H;

  const float* in_out  = (const float*)d_in[0];
  const float* in_sent = (const float*)d_in[1];
  const float* in_tmpl = (const float*)d_in[2];
  const float* in_Wg   = (const float*)d_in[3];
  const float* in_Ws   = (const float*)d_in[4];
  const float* in_Wt   = (const float*)d_in[5];
  const float* in_Wo   = (const float*)d_in[6];

  float* fus = (float*)d_out;         // (B,T,H)
  float* sw  = fus + BTH;             // (B,T,S)
  float* tw  = sw + BTS;              // (B,T,St)

  // ---- workspace ----
  char* p = (char*)d_ws;
  auto take = [&](long long bytes) { char* q = p; p += bytes; return q; };
  u16* out_h   = (u16*)take(BTH * 2);
  u16* out_lo  = (u16*)take(BTH * 2);
  u16* sent_h  = (u16*)take(BSH * 2);    // dead after sent-logits -> reused as ctx_s
  u16* sent_lo = (u16*)take(BSH * 2);    // dead after sent-logits -> reused as ctx_t
  u16* tmpl_h  = (u16*)take(BStH * 2);
  u16* tmpl_lo = (u16*)take(BStH * 2);
  u16* sentT   = (u16*)take(BSH * 2);    // (B,H,S)
  u16* tmplT   = (u16*)take(BStH * 2);   // (B,H,St)
  u16* Wg_h    = (u16*)take((long long)3 * H * H * 2);
  u16* Ws_h    = (u16*)take((long long)H * H * 2);
  u16* Wt_h    = (u16*)take((long long)H * H * 2);
  u16* Wo_h    = (u16*)take((long long)H * H * 2);
  u16* Ps      = (u16*)take(BTS * 2);
  u16* Pt      = (u16*)take(BTSt * 2);

  u16* ctx_s = sent_h;
  u16* ctx_t = sent_lo;

  dim3 thr(256);

  // conversions
  k_conv_hilo<<<2048, 256, 0, stream>>>(in_out, out_h, out_lo, (int)(BTH / 4));
  k_conv_w<<<1024, 256, 0, stream>>>(in_Wg, in_Ws, in_Wt, in_Wo, Wg_h, Ws_h, Wt_h, Wo_h);
  k_conv_T<<<dim3(H / 32, S / 32, B), dim3(32, 8), 0, stream>>>(in_sent, sent_h, sent_lo, sentT, S, H);
  k_conv_T<<<dim3(H / 32, St / 32, B), dim3(32, 8), 0, stream>>>(in_tmpl, tmpl_h, tmpl_lo, tmplT, St, H);

  // logits (3-pass split f16) -> d_out weight slots
  k_logits<<<dim3(S / 128, T / 128, B), thr, 0, stream>>>(
      out_h, out_lo, sent_h, sent_lo, (long long)S * H, sw, S, (long long)T * S);
  k_logits<<<dim3(St / 128, T / 128, B), thr, 0, stream>>>(
      out_h, out_lo, tmpl_h, tmpl_lo, (long long)St * H, tw, St, (long long)T * St);

  // softmax in place + f16 copy
  k_softmax<1024><<<(B * T) / 4, 256, 0, stream>>>(sw, Ps);
  k_softmax<512><<<(B * T) / 4, 256, 0, stream>>>(tw, Pt);

  // PV -> ctx (f16)
  k_pv<<<dim3(H / 128, T / 128, B), thr, 0, stream>>>(
      Ps, sentT, S, (long long)T * S, (long long)H * S, ctx_s, TH);
  k_pv<<<dim3(H / 128, T / 128, B), thr, 0, stream>>>(
      Pt, tmplT, St, (long long)T * St, (long long)H * St, ctx_t, TH);

  // fused gate + fusion: tanh((1-g)*ctx_s@Ws + g*ctx_t@Wt + out@Wo), g = sigmoid(cat@Wg^T)
  k_fusion4<<<dim3(H / 128, (B * T) / 128), thr, 0, stream>>>(
      ctx_s, ctx_t, out_h, Wg_h, Ws_h, Wt_h, Wo_h, fus);
}

// Round 11
// 352.460 us; speedup vs baseline: 1.2391x; 1.1384x over previous
//
#include <hip/hip_runtime.h>
#include <stdint.h>

typedef unsigned short u16;
typedef float    f32x4 __attribute__((ext_vector_type(4)));
typedef _Float16 f16x8 __attribute__((ext_vector_type(8)));
typedef _Float16 f16x4 __attribute__((ext_vector_type(4)));

__device__ __forceinline__ u16 f2h(float f) {
  _Float16 h = (_Float16)f;  // v_cvt_f16_f32, RNE
  u16 u; __builtin_memcpy(&u, &h, 2); return u;
}
__device__ __forceinline__ float h2f(u16 u) {
  _Float16 h; __builtin_memcpy(&h, &u, 2); return (float)h;
}

__device__ __forceinline__ void mfma_f16(f32x4& c, f16x8 a, f16x8 b) {
  c = __builtin_amdgcn_mfma_f32_16x16x32_f16(a, b, c, 0, 0, 0);
}

// async global->LDS, 16B/lane; LDS dest = wave-uniform base, lane i lands at +i*16B
__device__ __forceinline__ void g2l16(const u16* g, u16* l) {
  __builtin_amdgcn_global_load_lds((const __attribute__((address_space(1))) void*)g,
                                   (__attribute__((address_space(3))) void*)l,
                                   16, 0, 0);
}

// generic XCD-chunk swizzle: XCD owns a contiguous slice of the linearized grid
// (row-panels unique per XCD; small shared operands hit L3). grid product % 8 == 0.
__device__ __forceinline__ void xcd_swz(int& bx, int& by, int& bz) {
  const int gx = gridDim.x, gy = gridDim.y;
  const int n = gx * gy * gridDim.z;
  const int lin = blockIdx.x + gx * (blockIdx.y + gy * blockIdx.z);
  const int q = n >> 3;
  const int s = (lin & 7) * q + (lin >> 3);
  bx = s % gx;
  const int t2 = s / gx;
  by = t2 % gy;
  bz = t2 / gy;
}

struct alignas(8) US4 { u16 a, b, c, d; };

// ---- output: f32 -> f16 hi + lo residual ----
__global__ void k_conv_hilo(const float* __restrict__ src, u16* __restrict__ hi,
                            u16* __restrict__ lo, int n4) {
  int i = blockIdx.x * blockDim.x + threadIdx.x;
  int stride = gridDim.x * blockDim.x;
  for (; i < n4; i += stride) {
    float4 v = reinterpret_cast<const float4*>(src)[i];
    US4 h, l;
    h.a = f2h(v.x); l.a = f2h(v.x - h2f(h.a));
    h.b = f2h(v.y); l.b = f2h(v.y - h2f(h.b));
    h.c = f2h(v.z); l.c = f2h(v.z - h2f(h.c));
    h.d = f2h(v.w); l.d = f2h(v.w - h2f(h.d));
    reinterpret_cast<US4*>(hi)[i] = h;
    reinterpret_cast<US4*>(lo)[i] = l;
  }
}

// ---- 4 weight matrices: f32 -> f16 ----
__global__ void k_conv_w(const float* __restrict__ s_wg, const float* __restrict__ s_ws,
                         const float* __restrict__ s_wt, const float* __restrict__ s_wo,
                         u16* __restrict__ d_wg, u16* __restrict__ d_ws,
                         u16* __restrict__ d_wt, u16* __restrict__ d_wo) {
  constexpr int N1 = 786432;   // 3*1024*1024/4
  constexpr int N2 = 262144;   // 1024*1024/4
  constexpr int total = N1 + 3 * N2;
  int i = blockIdx.x * blockDim.x + threadIdx.x;
  int stride = gridDim.x * blockDim.x;
  for (; i < total; i += stride) {
    const float* s; u16* d; int j;
    if (i < N1)                { s = s_wg; d = d_wg; j = i; }
    else if (i < N1 + N2)      { s = s_ws; d = d_ws; j = i - N1; }
    else if (i < N1 + 2 * N2)  { s = s_wt; d = d_wt; j = i - N1 - N2; }
    else                       { s = s_wo; d = d_wo; j = i - N1 - 2 * N2; }
    float4 v = reinterpret_cast<const float4*>(s)[j];
    US4 h; h.a = f2h(v.x); h.b = f2h(v.y); h.c = f2h(v.z); h.d = f2h(v.w);
    reinterpret_cast<US4*>(d)[j] = h;
  }
}

// ---- encoders: f32 (B,R,C) -> f16 hi, f16 lo, f16 hi^T (B,C,R) ----
__global__ __launch_bounds__(256)
void k_conv_T(const float* __restrict__ src, u16* __restrict__ dh, u16* __restrict__ dl,
              u16* __restrict__ dt, int R, int C) {
  __shared__ u16 t[32][33];
  const int b = blockIdx.z;
  const float* s = src + (size_t)b * R * C;
  u16* dhb = dh + (size_t)b * R * C;
  u16* dlb = dl + (size_t)b * R * C;
  u16* dtb = dt + (size_t)b * R * C;
  const int c0 = blockIdx.x * 32, r0 = blockIdx.y * 32;
  const int tx = threadIdx.x, ty = threadIdx.y;
#pragma unroll
  for (int j = ty; j < 32; j += 8) {
    const size_t idx = (size_t)(r0 + j) * C + (c0 + tx);
    float x = s[idx];
    u16 h = f2h(x);
    dhb[idx] = h;
    dlb[idx] = f2h(x - h2f(h));
    t[j][tx] = h;
  }
  __syncthreads();
#pragma unroll
  for (int j = ty; j < 32; j += 8)
    dtb[(size_t)(c0 + j) * R + (r0 + tx)] = t[tx][j];
}

// ---- softmax (one wave per row): f32 in place + f16 copy ----
template<int L>
__global__ __launch_bounds__(256)
void k_softmax(float* __restrict__ io, u16* __restrict__ pb) {
  const int lane = threadIdx.x & 63;
  const size_t r = (size_t)blockIdx.x * 4 + (threadIdx.x >> 6);
  float* row = io + r * L;
  u16* prow = pb + r * L;
  constexpr int NV = L / 64;
  float v[NV];
  float mx = -3.4e38f;
#pragma unroll
  for (int j = 0; j < NV; ++j) { v[j] = row[lane + j * 64]; mx = fmaxf(mx, v[j]); }
#pragma unroll
  for (int s = 32; s; s >>= 1) mx = fmaxf(mx, __shfl_xor(mx, s));
  float sum = 0.f;
#pragma unroll
  for (int j = 0; j < NV; ++j) { v[j] = __expf(v[j] - mx); sum += v[j]; }
#pragma unroll
  for (int s = 32; s; s >>= 1) sum += __shfl_xor(sum, s);
  const float inv = 1.f / sum;
#pragma unroll
  for (int j = 0; j < NV; ++j) {
    float pv = v[j] * inv;
    row[lane + j * 64] = pv;
    prow[lane + j * 64] = f2h(pv);
  }
}

// ================= GEMM cores (BM=BN=128, 4 waves 2x2, 64x64 per wave) =================
struct TC { int wv, sr, sc, wm, wn, fr, kq; };

__device__ __forceinline__ TC make_tc(int tid) {
  TC t;
  const int lane = tid & 63;
  t.wv = tid >> 6;
  t.sr = lane >> 2;
  t.sc = (lane & 3) * 8;
  t.wm = t.wv >> 1;
  t.wn = t.wv & 1;
  t.fr = lane & 15;
  t.kq = (lane >> 4) * 8;
  return t;
}

constexpr int SUB = 128 * 32;   // one [128][32] sub-tile (8 KB)

// ---- pass64: 2-phase dbuf, BK=64 as two [128][32] sub-tiles (bank-clean ds_read) ----
__device__ __forceinline__ void pass64(
    f32x4 (&acc)[16],
    const u16* __restrict__ A, int lda,
    const u16* __restrict__ B, int ldb,
    int K, u16* sA, u16* sB, const TC& t)
{
  const int nt = K / 64;
  auto stage = [&](int c, int k0) {
#pragma unroll
    for (int sub = 0; sub < 2; ++sub) {
      u16* dA = sA + c * (2 * SUB) + sub * SUB;
      u16* dB = sB + c * (2 * SUB) + sub * SUB;
      const u16* ar = A + (size_t)t.sr * lda + k0 + sub * 32 + t.sc;
      const u16* br = B + (size_t)t.sr * ldb + k0 + sub * 32 + t.sc;
      g2l16(ar + (size_t)(t.wv * 16) * lda, dA + (t.wv * 16) * 32);
      g2l16(ar + (size_t)((t.wv + 4) * 16) * lda, dA + ((t.wv + 4) * 16) * 32);
      g2l16(br + (size_t)(t.wv * 16) * ldb, dB + (t.wv * 16) * 32);
      g2l16(br + (size_t)((t.wv + 4) * 16) * ldb, dB + ((t.wv + 4) * 16) * 32);
    }
  };

  stage(0, 0);
  __syncthreads();
  int c = 0;
  for (int it = 0; it < nt; ++it) {
    if (it + 1 < nt) stage(c ^ 1, (it + 1) * 64);   // overlaps MFMA below
#pragma unroll
    for (int sub = 0; sub < 2; ++sub) {
      const u16* bA = sA + c * (2 * SUB) + sub * SUB;
      const u16* bB = sB + c * (2 * SUB) + sub * SUB;
      f16x8 ah[4], bh[4];
#pragma unroll
      for (int i = 0; i < 4; ++i) {
        ah[i] = *reinterpret_cast<const f16x8*>(&bA[(t.wm * 64 + i * 16 + t.fr) * 32 + t.kq]);
        bh[i] = *reinterpret_cast<const f16x8*>(&bB[(t.wn * 64 + i * 16 + t.fr) * 32 + t.kq]);
      }
#pragma unroll
      for (int i = 0; i < 4; ++i)
#pragma unroll
        for (int j = 0; j < 4; ++j)
          mfma_f16(acc[i * 4 + j], ah[i], bh[j]);
    }
    __syncthreads();
    c ^= 1;
  }
}

// ---- pass32s: hi/lo split (3 MFMA/frag), 2-phase dbuf, BK=32 ----
__device__ __forceinline__ void pass32s(
    f32x4 (&acc)[16],
    const u16* __restrict__ A, const u16* __restrict__ Al, int lda,
    const u16* __restrict__ B, const u16* __restrict__ Bl, int ldb,
    int K, u16* sA, u16* sAl, u16* sB, u16* sBl, const TC& t)
{
  const int nt = K / 32;
  auto stage = [&](int c, int k0) {
    u16* dA = sA + c * SUB;  u16* dB = sB + c * SUB;
    u16* dAl = sAl + c * SUB; u16* dBl = sBl + c * SUB;
    const u16* ar = A + (size_t)t.sr * lda + k0 + t.sc;
    const u16* br = B + (size_t)t.sr * ldb + k0 + t.sc;
    const u16* alr = Al + (size_t)t.sr * lda + k0 + t.sc;
    const u16* blr = Bl + (size_t)t.sr * ldb + k0 + t.sc;
    g2l16(ar + (size_t)(t.wv * 16) * lda, dA + (t.wv * 16) * 32);
    g2l16(ar + (size_t)((t.wv + 4) * 16) * lda, dA + ((t.wv + 4) * 16) * 32);
    g2l16(br + (size_t)(t.wv * 16) * ldb, dB + (t.wv * 16) * 32);
    g2l16(br + (size_t)((t.wv + 4) * 16) * ldb, dB + ((t.wv + 4) * 16) * 32);
    g2l16(alr + (size_t)(t.wv * 16) * lda, dAl + (t.wv * 16) * 32);
    g2l16(alr + (size_t)((t.wv + 4) * 16) * lda, dAl + ((t.wv + 4) * 16) * 32);
    g2l16(blr + (size_t)(t.wv * 16) * ldb, dBl + (t.wv * 16) * 32);
    g2l16(blr + (size_t)((t.wv + 4) * 16) * ldb, dBl + ((t.wv + 4) * 16) * 32);
  };

  stage(0, 0);
  __syncthreads();
  int c = 0;
  for (int it = 0; it < nt; ++it) {
    if (it + 1 < nt) stage(c ^ 1, (it + 1) * 32);
    const u16* bA = sA + c * SUB;  const u16* bB = sB + c * SUB;
    const u16* bAl = sAl + c * SUB; const u16* bBl = sBl + c * SUB;
    f16x8 ah[4], bh[4], al[4], bl[4];
#pragma unroll
    for (int i = 0; i < 4; ++i) {
      ah[i] = *reinterpret_cast<const f16x8*>(&bA[(t.wm * 64 + i * 16 + t.fr) * 32 + t.kq]);
      bh[i] = *reinterpret_cast<const f16x8*>(&bB[(t.wn * 64 + i * 16 + t.fr) * 32 + t.kq]);
      al[i] = *reinterpret_cast<const f16x8*>(&bAl[(t.wm * 64 + i * 16 + t.fr) * 32 + t.kq]);
      bl[i] = *reinterpret_cast<const f16x8*>(&bBl[(t.wn * 64 + i * 16 + t.fr) * 32 + t.kq]);
    }
#pragma unroll
    for (int i = 0; i < 4; ++i)
#pragma unroll
      for (int j = 0; j < 4; ++j) {
        mfma_f16(acc[i * 4 + j], ah[i], bh[j]);
        mfma_f16(acc[i * 4 + j], al[i], bh[j]);
        mfma_f16(acc[i * 4 + j], ah[i], bl[j]);
      }
    __syncthreads();
    c ^= 1;
  }
}

// ---- pass32d: ONE A staged, TWO B targets (Z and W accumulators), 2-phase dbuf ----
__device__ __forceinline__ void pass32d(
    f32x4 (&accZ)[16], f32x4 (&accW)[16],
    const u16* __restrict__ A, int lda,
    const u16* __restrict__ B0, int ldb0,
    const u16* __restrict__ B1, int ldb1,
    int K, u16* sA, u16* sB0, u16* sB1, const TC& t)
{
  const int nt = K / 32;
  auto stage = [&](int c, int k0) {
    u16* dA = sA + c * SUB;
    u16* d0 = sB0 + c * SUB;
    u16* d1 = sB1 + c * SUB;
    const u16* ar = A + (size_t)t.sr * lda + k0 + t.sc;
    const u16* b0 = B0 + (size_t)t.sr * ldb0 + k0 + t.sc;
    const u16* b1 = B1 + (size_t)t.sr * ldb1 + k0 + t.sc;
    g2l16(ar + (size_t)(t.wv * 16) * lda, dA + (t.wv * 16) * 32);
    g2l16(ar + (size_t)((t.wv + 4) * 16) * lda, dA + ((t.wv + 4) * 16) * 32);
    g2l16(b0 + (size_t)(t.wv * 16) * ldb0, d0 + (t.wv * 16) * 32);
    g2l16(b0 + (size_t)((t.wv + 4) * 16) * ldb0, d0 + ((t.wv + 4) * 16) * 32);
    g2l16(b1 + (size_t)(t.wv * 16) * ldb1, d1 + (t.wv * 16) * 32);
    g2l16(b1 + (size_t)((t.wv + 4) * 16) * ldb1, d1 + ((t.wv + 4) * 16) * 32);
  };

  stage(0, 0);
  __syncthreads();
  int c = 0;
  for (int it = 0; it < nt; ++it) {
    if (it + 1 < nt) stage(c ^ 1, (it + 1) * 32);
    const u16* bA = sA + c * SUB;
    f16x8 ah[4];
#pragma unroll
    for (int i = 0; i < 4; ++i)
      ah[i] = *reinterpret_cast<const f16x8*>(&bA[(t.wm * 64 + i * 16 + t.fr) * 32 + t.kq]);
    {
      const u16* b0 = sB0 + c * SUB;
      f16x8 bh[4];
#pragma unroll
      for (int j = 0; j < 4; ++j)
        bh[j] = *reinterpret_cast<const f16x8*>(&b0[(t.wn * 64 + j * 16 + t.fr) * 32 + t.kq]);
#pragma unroll
      for (int i = 0; i < 4; ++i)
#pragma unroll
        for (int j = 0; j < 4; ++j)
          mfma_f16(accZ[i * 4 + j], ah[i], bh[j]);
    }
    {
      const u16* b1 = sB1 + c * SUB;
      f16x8 bh[4];
#pragma unroll
      for (int j = 0; j < 4; ++j)
        bh[j] = *reinterpret_cast<const f16x8*>(&b1[(t.wn * 64 + j * 16 + t.fr) * 32 + t.kq]);
#pragma unroll
      for (int i = 0; i < 4; ++i)
#pragma unroll
        for (int j = 0; j < 4; ++j)
          mfma_f16(accW[i * 4 + j], ah[i], bh[j]);
    }
    __syncthreads();
    c ^= 1;
  }
}

// ---- logits: split hi/lo, f32 out (grid: (N/128, T/128, B)) ----
__global__ __launch_bounds__(256, 2)
void k_logits(const u16* __restrict__ Ah, const u16* __restrict__ Al,
              const u16* __restrict__ Bh, const u16* __restrict__ Bl,
              long long strB, float* __restrict__ Cf, int ldc, long long strC)
{
  __shared__ __align__(16) u16 sA[2 * SUB], sB[2 * SUB], sAl[2 * SUB], sBl[2 * SUB];
  int bx, by, bz;
  xcd_swz(bx, by, bz);
  const TC t = make_tc(threadIdx.x);

  const size_t aoff = (size_t)bz * (1024 * 1024) + (size_t)by * 128 * 1024;
  const size_t boff = (size_t)bz * strB + (size_t)bx * 128 * 1024;

  f32x4 acc[16];
#pragma unroll
  for (int i = 0; i < 16; ++i) acc[i] = f32x4{0.f, 0.f, 0.f, 0.f};

  pass32s(acc, Ah + aoff, Al + aoff, 1024, Bh + boff, Bl + boff, 1024, 1024,
          sA, sAl, sB, sBl, t);

  const size_t cbse = (size_t)bz * strC;
  const int row0 = by * 128 + t.wm * 64;
  const int col0 = bx * 128 + t.wn * 64;
  const int fq = ((threadIdx.x & 63) >> 4) * 4;
#pragma unroll
  for (int i = 0; i < 4; ++i)
#pragma unroll
    for (int j = 0; j < 4; ++j) {
      const int c = col0 + j * 16 + t.fr;
#pragma unroll
      for (int q = 0; q < 4; ++q)
        Cf[cbse + (size_t)(row0 + i * 16 + fq + q) * ldc + c] = acc[i * 4 + j][q];
    }
}

// ---- PV: f16 out (grid: (H/128, T/128, B); XCD chunk -> batch-local L2 reuse) ----
__global__ __launch_bounds__(256, 2)
void k_pv(const u16* __restrict__ A, const u16* __restrict__ Bt, int ld,
          long long strA, long long strB, u16* __restrict__ Cb, long long strC)
{
  __shared__ __align__(16) u16 sA[2 * 2 * SUB], sB[2 * 2 * SUB];
  int bx, by, bz;
  xcd_swz(bx, by, bz);
  const TC t = make_tc(threadIdx.x);

  f32x4 acc[16];
#pragma unroll
  for (int i = 0; i < 16; ++i) acc[i] = f32x4{0.f, 0.f, 0.f, 0.f};

  pass64(acc, A + (size_t)bz * strA + (size_t)by * 128 * ld, ld,
         Bt + (size_t)bz * strB + (size_t)bx * 128 * ld, ld, ld, sA, sB, t);

  const size_t cbse = (size_t)bz * strC;
  const int row0 = by * 128 + t.wm * 64;
  const int col0 = bx * 128 + t.wn * 64;
  const int fq = ((threadIdx.x & 63) >> 4) * 4;
#pragma unroll
  for (int i = 0; i < 4; ++i)
#pragma unroll
    for (int j = 0; j < 4; ++j) {
      const int c = col0 + j * 16 + t.fr;
#pragma unroll
      for (int q = 0; q < 4; ++q)
        Cb[cbse + (size_t)(row0 + i * 16 + fq + q) * 1024 + c] = f2h(acc[i * 4 + j][q]);
    }
}

// ---- fusion4d: 3 dual passes — each A source staged once feeds (Wg seg, W) ----
// z accumulates across passes; S,T parked as f16; epilogue tanh(S + g(T-S) + O).
__global__ __launch_bounds__(256, 2)
void k_fusion4(const u16* __restrict__ ctx_s, const u16* __restrict__ ctx_t,
               const u16* __restrict__ outh,
               const u16* __restrict__ Wg, const u16* __restrict__ Ws,
               const u16* __restrict__ Wt, const u16* __restrict__ Wo,
               float* __restrict__ fus)
{
  constexpr int H = 1024;
  __shared__ __align__(16) u16 sA[2 * SUB], sB0[2 * SUB], sB1[2 * SUB];  // 48 KB

  int bx, by, bz;
  xcd_swz(bx, by, bz);           // grid (8, 64, 1)
  const TC t = make_tc(threadIdx.x);

  const size_t aoff = (size_t)by * 128 * H;
  const size_t wgoff = (size_t)bx * 128 * (3 * H);
  const int row0 = by * 128 + t.wm * 64;
  const int col0 = bx * 128 + t.wn * 64;
  const int fq = ((threadIdx.x & 63) >> 4) * 4;

  f32x4 accZ[16], accW[16];
#pragma unroll
  for (int i = 0; i < 16; ++i) {
    accZ[i] = f32x4{0.f, 0.f, 0.f, 0.f};
    accW[i] = f32x4{0.f, 0.f, 0.f, 0.f};
  }

  // pass 0: A = ctx_s, B0 = Wg seg0, B1 = Ws
  pass32d(accZ, accW, ctx_s + aoff, H, Wg + wgoff, 3 * H,
          Ws + (size_t)bx * 128 * H, H, H, sA, sB0, sB1, t);
  f16x4 S16[16];
#pragma unroll
  for (int f = 0; f < 16; ++f) {
#pragma unroll
    for (int q = 0; q < 4; ++q) S16[f][q] = (_Float16)accW[f][q];
    accW[f] = f32x4{0.f, 0.f, 0.f, 0.f};
  }

  // pass 1: A = ctx_t, B0 = Wg seg1, B1 = Wt
  pass32d(accZ, accW, ctx_t + aoff, H, Wg + wgoff + H, 3 * H,
          Wt + (size_t)bx * 128 * H, H, H, sA, sB0, sB1, t);
  f16x4 T16[16];
#pragma unroll
  for (int f = 0; f < 16; ++f) {
#pragma unroll
    for (int q = 0; q < 4; ++q) T16[f][q] = (_Float16)accW[f][q];
    accW[f] = f32x4{0.f, 0.f, 0.f, 0.f};
  }

  // pass 2: A = outh, B0 = Wg seg2, B1 = Wo
  pass32d(accZ, accW, outh + aoff, H, Wg + wgoff + 2 * H, 3 * H,
          Wo + (size_t)bx * 128 * H, H, H, sA, sB0, sB1, t);

  // epilogue: g = sigmoid(z); fus = tanh(S + g*(T-S) + O)
#pragma unroll
  for (int i = 0; i < 4; ++i)
#pragma unroll
    for (int j = 0; j < 4; ++j) {
      const int f = i * 4 + j;
      const int c = col0 + j * 16 + t.fr;
#pragma unroll
      for (int q = 0; q < 4; ++q) {
        const int r = row0 + i * 16 + fq + q;
        const float g = 1.f / (1.f + __expf(-accZ[f][q]));
        const float sv = (float)S16[f][q];
        const float tv = (float)T16[f][q];
        float x = sv + g * (tv - sv) + accW[f][q];
        float ax = fabsf(x);
        float e = __expf(-2.f * ax);
        float th = (1.f - e) / (1.f + e);
        fus[(size_t)r * H + c] = copysignf(th, x);
      }
    }
}

extern "C" void kernel_launch(void* const* d_in, const int* in_sizes, int n_in,
                              void* d_out, int out_size, void* d_ws, size_t ws_size,
                              hipStream_t stream) {
  (void)in_sizes; (void)n_in; (void)out_size; (void)ws_size;
  constexpr int B = 8, T = 1024, S = 1024, St = 512, H = 1024;
  constexpr long long BTH = (long long)B * T * H;
  constexpr long long BSH = (long long)B * S * H;
  constexpr long long BStH = (long long)B * St * H;
  constexpr long long BTS = (long long)B * T * S;
  constexpr long long BTSt = (long long)B * T * St;
  constexpr long long TH = (long long)T * H;

  const float* in_out  = (const float*)d_in[0];
  const float* in_sent = (const float*)d_in[1];
  const float* in_tmpl = (const float*)d_in[2];
  const float* in_Wg   = (const float*)d_in[3];
  const float* in_Ws   = (const float*)d_in[4];
  const float* in_Wt   = (const float*)d_in[5];
  const float* in_Wo   = (const float*)d_in[6];

  float* fus = (float*)d_out;         // (B,T,H)
  float* sw  = fus + BTH;             // (B,T,S)
  float* tw  = sw + BTS;              // (B,T,St)

  // ---- workspace ----
  char* p = (char*)d_ws;
  auto take = [&](long long bytes) { char* q = p; p += bytes; return q; };
  u16* out_h   = (u16*)take(BTH * 2);
  u16* out_lo  = (u16*)take(BTH * 2);
  u16* sent_h  = (u16*)take(BSH * 2);    // dead after sent-logits -> reused as ctx_s
  u16* sent_lo = (u16*)take(BSH * 2);    // dead after sent-logits -> reused as ctx_t
  u16* tmpl_h  = (u16*)take(BStH * 2);
  u16* tmpl_lo = (u16*)take(BStH * 2);
  u16* sentT   = (u16*)take(BSH * 2);    // (B,H,S)
  u16* tmplT   = (u16*)take(BStH * 2);   // (B,H,St)
  u16* Wg_h    = (u16*)take((long long)3 * H * H * 2);
  u16* Ws_h    = (u16*)take((long long)H * H * 2);
  u16* Wt_h    = (u16*)take((long long)H * H * 2);
  u16* Wo_h    = (u16*)take((long long)H * H * 2);
  u16* Ps      = (u16*)take(BTS * 2);
  u16* Pt      = (u16*)take(BTSt * 2);

  u16* ctx_s = sent_h;
  u16* ctx_t = sent_lo;

  dim3 thr(256);

  // conversions
  k_conv_hilo<<<2048, 256, 0, stream>>>(in_out, out_h, out_lo, (int)(BTH / 4));
  k_conv_w<<<1024, 256, 0, stream>>>(in_Wg, in_Ws, in_Wt, in_Wo, Wg_h, Ws_h, Wt_h, Wo_h);
  k_conv_T<<<dim3(H / 32, S / 32, B), dim3(32, 8), 0, stream>>>(in_sent, sent_h, sent_lo, sentT, S, H);
  k_conv_T<<<dim3(H / 32, St / 32, B), dim3(32, 8), 0, stream>>>(in_tmpl, tmpl_h, tmpl_lo, tmplT, St, H);

  // logits (3-pass split f16) -> d_out weight slots
  k_logits<<<dim3(S / 128, T / 128, B), thr, 0, stream>>>(
      out_h, out_lo, sent_h, sent_lo, (long long)S * H, sw, S, (long long)T * S);
  k_logits<<<dim3(St / 128, T / 128, B), thr, 0, stream>>>(
      out_h, out_lo, tmpl_h, tmpl_lo, (long long)St * H, tw, St, (long long)T * St);

  // softmax in place + f16 copy
  k_softmax<1024><<<(B * T) / 4, 256, 0, stream>>>(sw, Ps);
  k_softmax<512><<<(B * T) / 4, 256, 0, stream>>>(tw, Pt);

  // PV -> ctx (f16)
  k_pv<<<dim3(H / 128, T / 128, B), thr, 0, stream>>>(
      Ps, sentT, S, (long long)T * S, (long long)H * S, ctx_s, TH);
  k_pv<<<dim3(H / 128, T / 128, B), thr, 0, stream>>>(
      Pt, tmplT, St, (long long)T * St, (long long)H * St, ctx_t, TH);

  // fused gate + fusion, dual-B passes
  k_fusion4<<<dim3(H / 128, (B * T) / 128), thr, 0, stream>>>(
      ctx_s, ctx_t, out_h, Wg_h, Ws_h, Wt_h, Wo_h, fus);
}